// Round 19
// baseline (276.201 us; speedup 1.0000x reference)
//
#include <hip/hip_runtime.h>

typedef unsigned short ushort;
typedef __attribute__((ext_vector_type(8))) short short8;
typedef __attribute__((ext_vector_type(4))) float f32x4;

#define NH 16
#define DH 128
#define SEQ 2048
#define DMODEL 2048
#define GK 2048   // K dim for both GEMMs

__device__ __forceinline__ ushort f2bf(float f) {
  union { float f; unsigned u; } v; v.f = f;
  unsigned u = v.u;
  unsigned r = (u + 0x7fffu + ((u >> 16) & 1u)) >> 16;
  return (ushort)r;
}
__device__ __forceinline__ float bf2f(ushort h) {
  union { unsigned u; float f; } v; v.u = ((unsigned)h) << 16; return v.f;
}

__device__ __forceinline__ unsigned cvtpk(float lo, float hi) {
  unsigned r;
  asm("v_cvt_pk_bf16_f32 %0, %1, %2" : "=v"(r) : "v"(lo), "v"(hi));
  return r;
}

__device__ __forceinline__ void async16(const ushort* g, ushort* l) {
  __builtin_amdgcn_global_load_lds(
      (const __attribute__((address_space(1))) unsigned*)g,
      (__attribute__((address_space(3))) unsigned*)l, 16, 0, 0);
}

// staged chunk: 8 elements; F32=1 loads 2x float4 and converts at write time
template<int F32> struct Chunk;
template<> struct Chunk<0> {
  short8 v;
  __device__ __forceinline__ void load(const void* p) { v = *(const short8*)p; }
  __device__ __forceinline__ short8 get() const { return v; }
};
template<> struct Chunk<1> {
  f32x4 a, b;
  __device__ __forceinline__ void load(const void* p) {
    a = *(const f32x4*)p;
    b = *(const f32x4*)((const float*)p + 4);
  }
  __device__ __forceinline__ short8 get() const {
    union { unsigned u[4]; short8 s; } x;
    x.u[0] = cvtpk(a[0], a[1]); x.u[1] = cvtpk(a[2], a[3]);
    x.u[2] = cvtpk(b[0], b[1]); x.u[3] = cvtpk(b[2], b[3]);
    return x.s;
  }
};

// ---------------- 256xBN GEMM, reg-staged 2-tile pipeline, fused input cast ----
// (r15-r18 structure, passing: 512 threads = 8 waves (2M x 4N), wave tile
// 128 x BN/4, BK=64, 2 LDS slots, global->VGPR->LDS staging, 1 barrier/K-tile.)
// AF32/BF32: operand is fp32 in HBM; converted in the reg hop via v_cvt_pk_bf16_f32
// (same element indices -> same verified swizzle; col % 8 == 0 -> float4-aligned).
template<int MODE, int NTK, int BN, int AF32, int BF32>
__global__ __launch_bounds__(512, 1)
void gemmk(const void* __restrict__ A, const void* __restrict__ B, int N,
           ushort* __restrict__ oq, ushort* __restrict__ ok, ushort* __restrict__ ov,
           float* __restrict__ of) {
  constexpr int NF = BN / 64;              // B frags / wave; B chunks / thread
  constexpr int WN = BN / 4;               // wave N width
  __shared__ ushort As[2][256 * 64];       // 64 KB
  __shared__ ushort Bs[2][BN * 64];        // 2 * BN/8 KB
  const int tid = threadIdx.x;
  const int lane = tid & 63;
  const int w = tid >> 6;
  const int wm = w >> 2, wn = w & 3;
  const int g = lane >> 4, l16 = lane & 15;
  const int m0 = blockIdx.y * 256;
  const int n0 = blockIdx.x * BN;

  const int r0 = tid >> 3, sl = tid & 7;
  const int gcol = ((sl * 16) ^ ((r0 & 7) << 4)) >> 1;   // ELEMENT index (swizzled)
  const int ldsb = r0 * 64 + sl * 8;

  // typed element address helpers
  auto aAddr = [&](int row, int col) -> const void* {
    return AF32 ? (const void*)((const float*)A + (size_t)(m0 + row) * GK + col)
                : (const void*)((const ushort*)A + (size_t)(m0 + row) * GK + col);
  };
  auto bAddr = [&](int row, int col) -> const void* {
    return BF32 ? (const void*)((const float*)B + (size_t)(n0 + row) * GK + col)
                : (const void*)((const ushort*)B + (size_t)(n0 + row) * GK + col);
  };

  f32x4 acc[8][NF];
#pragma unroll
  for (int mf = 0; mf < 8; ++mf)
#pragma unroll
    for (int nf = 0; nf < NF; ++nf) acc[mf][nf] = (f32x4)0.f;

  Chunk<AF32> ra[4];
  Chunk<BF32> rb[NF];
  // ---- prologue: tiles 0 and 1 -> LDS ----
#pragma unroll
  for (int j = 0; j < 4; ++j)  ra[j].load(aAddr(j * 64 + r0, gcol));
#pragma unroll
  for (int j = 0; j < NF; ++j) rb[j].load(bAddr(j * 64 + r0, gcol));
#pragma unroll
  for (int j = 0; j < 4; ++j)  *(short8*)&As[0][j * 4096 + ldsb] = ra[j].get();
#pragma unroll
  for (int j = 0; j < NF; ++j) *(short8*)&Bs[0][j * 4096 + ldsb] = rb[j].get();
#pragma unroll
  for (int j = 0; j < 4; ++j)  ra[j].load(aAddr(j * 64 + r0, 64 + gcol));
#pragma unroll
  for (int j = 0; j < NF; ++j) rb[j].load(bAddr(j * 64 + r0, 64 + gcol));
#pragma unroll
  for (int j = 0; j < 4; ++j)  *(short8*)&As[1][j * 4096 + ldsb] = ra[j].get();
#pragma unroll
  for (int j = 0; j < NF; ++j) *(short8*)&Bs[1][j * 4096 + ldsb] = rb[j].get();
  __syncthreads();

  for (int t = 0; t < NTK; ++t) {
    const bool pre = (t + 2 < NTK);
    if (pre) {
      const int kt = (t + 2) * 64;
#pragma unroll
      for (int j = 0; j < 4; ++j)  ra[j].load(aAddr(j * 64 + r0, kt + gcol));
#pragma unroll
      for (int j = 0; j < NF; ++j) rb[j].load(bAddr(j * 64 + r0, kt + gcol));
    }
    __builtin_amdgcn_sched_barrier(0);     // pin load issue before compute

    const ushort* cA = As[t & 1];
    const ushort* cB = Bs[t & 1];
    short8 bfr[NF][2];
#pragma unroll
    for (int nf = 0; nf < NF; ++nf) {
      int row = wn * WN + nf * 16 + l16;
#pragma unroll
      for (int ks = 0; ks < 2; ++ks)
        bfr[nf][ks] = *(const short8*)&cB[row * 64 + (((ks * 64 + g * 16) ^ ((l16 & 7) << 4)) >> 1)];
    }
#pragma unroll
    for (int p = 0; p < 4; ++p) {
      short8 af[2][2];
#pragma unroll
      for (int mi = 0; mi < 2; ++mi) {
        int row = wm * 128 + (2 * p + mi) * 16 + l16;
#pragma unroll
        for (int ks = 0; ks < 2; ++ks)
          af[mi][ks] = *(const short8*)&cA[row * 64 + (((ks * 64 + g * 16) ^ ((l16 & 7) << 4)) >> 1)];
      }
      __builtin_amdgcn_s_setprio(1);
#pragma unroll
      for (int mi = 0; mi < 2; ++mi)
#pragma unroll
        for (int nf = 0; nf < NF; ++nf)
#pragma unroll
          for (int ks = 0; ks < 2; ++ks)
            acc[2 * p + mi][nf] = __builtin_amdgcn_mfma_f32_16x16x32_bf16(
                af[mi][ks], bfr[nf][ks], acc[2 * p + mi][nf], 0, 0, 0);
      __builtin_amdgcn_s_setprio(0);
    }

    __syncthreads();                       // readers done + vmcnt drain
    if (pre) {
      ushort* nA = (ushort*)As[t & 1];
      ushort* nB = (ushort*)Bs[t & 1];
#pragma unroll
      for (int j = 0; j < 4; ++j)  *(short8*)&nA[j * 4096 + ldsb] = ra[j].get();
#pragma unroll
      for (int j = 0; j < NF; ++j) *(short8*)&nB[j * 4096 + ldsb] = rb[j].get();
    }
  }

#pragma unroll
  for (int mf = 0; mf < 8; ++mf)
#pragma unroll
    for (int nf = 0; nf < NF; ++nf)
#pragma unroll
      for (int i = 0; i < 4; ++i) {
        int row = m0 + wm * 128 + mf * 16 + g * 4 + i;
        int col = n0 + wn * WN + nf * 16 + l16;
        float val = acc[mf][nf][i];
        if (MODE == 0) {
          int which = col >> 11;
          int r = col & 2047;
          int h = r >> 7, dh = r & 127;
          int b = row >> 11, s = row & 2047;
          size_t dst = ((size_t)(b * NH + h) * SEQ + s) * DH + dh;
          ushort* o = (which == 0) ? oq : (which == 1 ? ok : ov);
          o[dst] = f2bf(val);
        } else {
          of[(size_t)row * N + col] = val;
        }
      }
}

// ---------------- RoPE (in-place on head-major bf16 q,k) ----------------
__global__ void rope_kernel(ushort* __restrict__ q, ushort* __restrict__ k,
                            const int* __restrict__ spp) {
  int id = blockIdx.x * blockDim.x + threadIdx.x;   // < B*H*S*64
  int j = id & 63;
  int s = (id >> 6) & (SEQ - 1);
  int bh = id >> 17;
  size_t base = ((size_t)bh * SEQ + s) * DH;
  float pos = (float)(s + spp[0]);
  float ang = pos * __expf(-(float)j * (9.210340371976184f / 64.f)); // 1/10000^(j/64)
  float c = cosf(ang), sn = sinf(ang);
  float q1 = bf2f(q[base + j]), q2 = bf2f(q[base + 64 + j]);
  q[base + j]      = f2bf(q1 * c - q2 * sn);
  q[base + 64 + j] = f2bf(q2 * c + q1 * sn);
  float k1 = bf2f(k[base + j]), k2 = bf2f(k[base + 64 + j]);
  k[base + j]      = f2bf(k1 * c - k2 * sn);
  k[base + 64 + j] = f2bf(k2 * c + k1 * sn);
}

// ---------------- causal flash attention (r18 version, passing) ----------
__global__ __launch_bounds__(256, 2)
void attn_kernel(const ushort* __restrict__ Q, const ushort* __restrict__ K,
                 const ushort* __restrict__ V, ushort* __restrict__ O) {
  __shared__ ushort Ks[2][64 * 128];     // 32 KB
  __shared__ ushort Vt[2][128 * 72];     // 36 KB
  __shared__ ushort Ps[4][16 * 72];      // 9 KB
  const int tid = threadIdx.x;
  const int lane = tid & 63;
  const int w = tid >> 6;
  const int g = lane >> 4, l16 = lane & 15;
  const int h = blockIdx.y, b = blockIdx.z;
  const int bh = b * NH + h;
  const ushort* Qb = Q + (size_t)bh * SEQ * DH;
  const ushort* Kb = K + (size_t)bh * SEQ * DH;
  const ushort* Vb = V + (size_t)bh * SEQ * DH;
  const float scale2 = 0.08838834764831845f * 1.4426950408889634f;  // /sqrt(128) * log2e
  const float THR2   = 11.541560327111708f;                          // 8 * log2e

  const int vkv = (tid >> 3) * 2;       // 0..62
  const int vd0 = (tid & 7) * 16;       // 0..112
  const int vmask = (tid & 7) << 3;     // XOR swizzle ((d>>4)&7)<<3

  for (int pass = 0; pass < 2; ++pass) {
    const int qt = pass == 0 ? (31 - (int)blockIdx.x) : (int)blockIdx.x;
    const int q0 = qt * 64;
    const int nkt = qt + 1;

    short8 qf[4];
    {
      const ushort* qrow = Qb + (size_t)(q0 + w * 16 + l16) * DH;
#pragma unroll
      for (int ks = 0; ks < 4; ++ks) qf[ks] = *(const short8*)(qrow + ks * 32 + g * 8);
    }
    f32x4 oacc[8];
#pragma unroll
    for (int i = 0; i < 8; ++i) oacc[i] = (f32x4)0.f;
    float m_i[4], l_i[4];                 // l_i is a PER-LANE partial until epilogue
#pragma unroll
    for (int i = 0; i < 4; ++i) { m_i[i] = -INFINITY; l_i[i] = 0.f; }

#pragma unroll
    for (int it = 0; it < 4; ++it) {
      int ci = it * 256 + tid;
      int row = ci >> 4;
      int cb = ((ci & 15) * 16) ^ ((row & 7) << 4);
      async16(Kb + (size_t)row * DH + (cb >> 1), &Ks[0][ci * 8]);
    }
    {
      short8 vr[4];
      vr[0] = *(const short8*)(Vb + (size_t)vkv * DH + vd0);
      vr[1] = *(const short8*)(Vb + (size_t)vkv * DH + vd0 + 8);
      vr[2] = *(const short8*)(Vb + (size_t)(vkv + 1) * DH + vd0);
      vr[3] = *(const short8*)(Vb + (size_t)(vkv + 1) * DH + vd0 + 8);
#pragma unroll
      for (int j = 0; j < 16; ++j) {
        int d = vd0 + j;
        const ushort* a = (const ushort*)&vr[j >> 3];
        const ushort* c = (const ushort*)&vr[2 + (j >> 3)];
        unsigned val = (unsigned)a[j & 7] | ((unsigned)c[j & 7] << 16);
        *(unsigned*)&Vt[0][d * 72 + (vkv ^ vmask)] = val;
      }
    }
    __syncthreads();

    int cur = 0;
    for (int t = 0; t < nkt; ++t) {
      const int k0 = t * 64;
      const int nxt = cur ^ 1;
      const bool pre = (t + 1 < nkt);
      short8 vr[4];
      if (pre) {
        const int kn = (t + 1) * 64;
#pragma unroll
        for (int it = 0; it < 4; ++it) {
          int ci = it * 256 + tid;
          int row = ci >> 4;
          int cb = ((ci & 15) * 16) ^ ((row & 7) << 4);
          async16(Kb + (size_t)(kn + row) * DH + (cb >> 1), &Ks[nxt][ci * 8]);
        }
        vr[0] = *(const short8*)(Vb + (size_t)(kn + vkv) * DH + vd0);
        vr[1] = *(const short8*)(Vb + (size_t)(kn + vkv) * DH + vd0 + 8);
        vr[2] = *(const short8*)(Vb + (size_t)(kn + vkv + 1) * DH + vd0);
        vr[3] = *(const short8*)(Vb + (size_t)(kn + vkv + 1) * DH + vd0 + 8);
      }

      // ---- QK^T : S[16 q][64 keys] per wave ----
      f32x4 sacc[4];
#pragma unroll
      for (int nf = 0; nf < 4; ++nf) sacc[nf] = (f32x4)0.f;
      __builtin_amdgcn_s_setprio(1);
#pragma unroll
      for (int nf = 0; nf < 4; ++nf) {
        int row = nf * 16 + l16;
#pragma unroll
        for (int ks = 0; ks < 4; ++ks) {
          int cb = (ks * 64 + g * 16) ^ ((l16 & 7) << 4);
          short8 kf = *(const short8*)&Ks[cur][row * 128 + (cb >> 1)];
          sacc[nf] = __builtin_amdgcn_mfma_f32_16x16x32_bf16(qf[ks], kf, sacc[nf], 0, 0, 0);
        }
      }
      __builtin_amdgcn_s_setprio(0);

      // ---- online softmax, exp2 domain (diag-only mask; defer-max) ----
      float pv[4][4], mxr[4];
#pragma unroll
      for (int i = 0; i < 4; ++i)
#pragma unroll
        for (int nf = 0; nf < 4; ++nf) pv[i][nf] = sacc[nf][i] * scale2;
      if (t == nkt - 1) {                  // diagonal tile: apply causal mask
#pragma unroll
        for (int i = 0; i < 4; ++i) {
          int qrow = q0 + w * 16 + g * 4 + i;
#pragma unroll
          for (int nf = 0; nf < 4; ++nf)
            if (k0 + nf * 16 + l16 > qrow) pv[i][nf] = -INFINITY;
        }
      }
#pragma unroll
      for (int i = 0; i < 4; ++i) {
        float mx = fmaxf(fmaxf(pv[i][0], pv[i][1]), fmaxf(pv[i][2], pv[i][3]));
#pragma unroll
        for (int d = 1; d < 16; d <<= 1) mx = fmaxf(mx, __shfl_xor(mx, d, 64));
        mxr[i] = mx;
      }
      int need = 0;
#pragma unroll
      for (int i = 0; i < 4; ++i) need |= (mxr[i] > m_i[i] + THR2) ? 1 : 0;
      if (__any(need)) {
#pragma unroll
        for (int i = 0; i < 4; ++i) {
          float mnew = fmaxf(m_i[i], mxr[i]);
          float alpha = exp2f(m_i[i] - mnew);
          l_i[i] *= alpha;
          m_i[i] = mnew;
#pragma unroll
          for (int nf2 = 0; nf2 < 8; ++nf2) oacc[nf2][i] *= alpha;
        }
      }
#pragma unroll
      for (int i = 0; i < 4; ++i) {
        float p[4];
#pragma unroll
        for (int nf = 0; nf < 4; ++nf) p[nf] = exp2f(pv[i][nf] - m_i[i]);
        l_i[i] += (p[0] + p[1]) + (p[2] + p[3]);   // per-lane partial, no shuffle
#pragma unroll
        for (int nf = 0; nf < 4; ++nf)
          Ps[w][(g * 4 + i) * 72 + nf * 16 + l16] = f2bf(p[nf]);
      }
      __asm__ volatile("s_waitcnt lgkmcnt(0)" ::: "memory");
      __builtin_amdgcn_sched_barrier(0);

      // ---- PV: O[16 q][128 dh] += P[16][64] @ V[64][128] ----
      __builtin_amdgcn_s_setprio(1);
#pragma unroll
      for (int kvh = 0; kvh < 2; ++kvh) {
        short8 pa = *(const short8*)&Ps[w][l16 * 72 + kvh * 32 + g * 8];
#pragma unroll
        for (int nf2 = 0; nf2 < 8; ++nf2) {
          int cb = (kvh * 32 + g * 8) ^ (nf2 * 8);
          short8 vf = *(const short8*)&Vt[cur][(nf2 * 16 + l16) * 72 + cb];
          oacc[nf2] = __builtin_amdgcn_mfma_f32_16x16x32_bf16(pa, vf, oacc[nf2], 0, 0, 0);
        }
      }
      __builtin_amdgcn_s_setprio(0);

      if (pre) {
#pragma unroll
        for (int j = 0; j < 16; ++j) {
          int d = vd0 + j;
          const ushort* a = (const ushort*)&vr[j >> 3];
          const ushort* c = (const ushort*)&vr[2 + (j >> 3)];
          unsigned val = (unsigned)a[j & 7] | ((unsigned)c[j & 7] << 16);
          *(unsigned*)&Vt[nxt][d * 72 + (vkv ^ vmask)] = val;
        }
      }
      __syncthreads();
      cur = nxt;
    }

    // ---- epilogue: single l-reduction across the 16-lane row group ----
#pragma unroll
    for (int i = 0; i < 4; ++i) {
      float sum = l_i[i];
#pragma unroll
      for (int d = 1; d < 16; d <<= 1) sum += __shfl_xor(sum, d, 64);
      float inv = 1.f / sum;
      int row = q0 + w * 16 + g * 4 + i;
      size_t obase = ((size_t)b * SEQ + row) * DMODEL + h * DH;
#pragma unroll
      for (int nf2 = 0; nf2 < 8; ++nf2)
        O[obase + nf2 * 16 + l16] = f2bf(oacc[nf2][i] * inv);
    }
  }
}

// ---------------- launch ----------------
extern "C" void kernel_launch(void* const* d_in, const int* in_sizes, int n_in,
                              void* d_out, int out_size, void* d_ws, size_t ws_size,
                              hipStream_t stream) {
  const float* x    = (const float*)d_in[0];
  const float* wqkv = (const float*)d_in[1];
  const float* wout = (const float*)d_in[2];
  const int*   spp  = (const int*)d_in[3];
  float* out = (float*)d_out;

  ushort* ws = (ushort*)d_ws;
  ushort* q   = ws;                       // 8,388,608 elems each
  ushort* k   = q + 8388608;
  ushort* v   = k + 8388608;
  ushort* ao  = v + 8388608;

  // GEMM1: A=x (fp32), B=wqkv (fp32), fused cast in staging.
  // BN=192 -> grid 32x16 = 512 blocks = exactly 2 rounds on 256 CUs.
  gemmk<0, 32, 192, 1, 1><<<dim3(6144 / 192, 4096 / 256, 1), 512, 0, stream>>>(
      x, wqkv, 6144, q, k, v, nullptr);

  rope_kernel<<<4194304 / 256, 256, 0, stream>>>(q, k, spp);

  attn_kernel<<<dim3(16, NH, 2), 256, 0, stream>>>(q, k, v, ao);

  // GEMM2: A=ao (bf16), B=wout (fp32, fused cast).
  // BN=128 -> grid 16x16 = 256 blocks = exactly 1 round, full K.
  gemmk<1, 32, 128, 0, 1><<<dim3(2048 / 128, 4096 / 256, 1), 512, 0, stream>>>(
      ao, wout, 2048, nullptr, nullptr, nullptr, out);
}

// Round 20
// 259.496 us; speedup vs baseline: 1.0644x; 1.0644x over previous
//
#include <hip/hip_runtime.h>

typedef unsigned short ushort;
typedef __attribute__((ext_vector_type(8))) short short8;
typedef __attribute__((ext_vector_type(4))) float f32x4;

#define NH 16
#define DH 128
#define SEQ 2048
#define DMODEL 2048
#define GK 2048   // K dim for both GEMMs

__device__ __forceinline__ ushort f2bf(float f) {
  union { float f; unsigned u; } v; v.f = f;
  unsigned u = v.u;
  unsigned r = (u + 0x7fffu + ((u >> 16) & 1u)) >> 16;
  return (ushort)r;
}
__device__ __forceinline__ float bf2f(ushort h) {
  union { unsigned u; float f; } v; v.u = ((unsigned)h) << 16; return v.f;
}

__device__ __forceinline__ void async16(const ushort* g, ushort* l) {
  __builtin_amdgcn_global_load_lds(
      (const __attribute__((address_space(1))) unsigned*)g,
      (__attribute__((address_space(3))) unsigned*)l, 16, 0, 0);
}

// ---------------- fused cast fp32 -> bf16 for x, wqkv, wout ----------------
#define NX  2097152   // x      f4 count
#define NWQ 3145728   // wqkv   f4 count
#define NWO 1048576   // wout   f4 count
__global__ void cast3_kernel(const float* __restrict__ x, const float* __restrict__ wq,
                             const float* __restrict__ wo, ushort* __restrict__ xb,
                             ushort* __restrict__ wqb, ushort* __restrict__ wob) {
  int i = blockIdx.x * blockDim.x + threadIdx.x;
  int stride = gridDim.x * blockDim.x;
  for (; i < NX + NWQ + NWO; i += stride) {
    const float* s; ushort* d; int j;
    if (i < NX)            { s = x;  d = xb;  j = i; }
    else if (i < NX + NWQ) { s = wq; d = wqb; j = i - NX; }
    else                   { s = wo; d = wob; j = i - NX - NWQ; }
    float4 v = ((const float4*)s)[j];
    unsigned long long p = (unsigned long long)f2bf(v.x)
                         | ((unsigned long long)f2bf(v.y) << 16)
                         | ((unsigned long long)f2bf(v.z) << 32)
                         | ((unsigned long long)f2bf(v.w) << 48);
    ((unsigned long long*)d)[j] = p;
  }
}

// ---------------- BMxBN GEMM, reg-staged 2-tile-deep pipeline ----------------
// (r15-r18 structure, passing: 512 threads = 8 waves (2M x 4N), wave tile
// (BM/2) x (BN/4), BK=64, 2 LDS slots, global->VGPR->LDS staging,
// 1 barrier/K-tile.  MF=BM/32 M-frags, NF=BN/64 N-frags, AC=BM/64 A-chunks.)
template<int MODE, int NTK, int BM, int BN>
__global__ __launch_bounds__(512, 1)
void gemmk(const ushort* __restrict__ A, const ushort* __restrict__ B, int N,
           ushort* __restrict__ oq, ushort* __restrict__ ok, ushort* __restrict__ ov,
           float* __restrict__ of) {
  constexpr int NF = BN / 64;              // B frags / wave; B chunks / thread
  constexpr int MF = BM / 32;              // M frags / wave
  constexpr int AC = BM / 64;              // A chunks / thread
  __shared__ ushort As[2][BM * 64];
  __shared__ ushort Bs[2][BN * 64];
  const int tid = threadIdx.x;
  const int lane = tid & 63;
  const int w = tid >> 6;
  const int wm = w >> 2, wn = w & 3;
  const int g = lane >> 4, l16 = lane & 15;
  const int m0 = blockIdx.y * BM;
  const int n0 = blockIdx.x * BN;
  const ushort* Ablk = A + (size_t)m0 * GK;
  const ushort* Bblk = B + (size_t)n0 * GK;

  const int r0 = tid >> 3, sl = tid & 7;
  const int gcol = ((sl * 16) ^ ((r0 & 7) << 4)) >> 1;
  const int ldsb = r0 * 64 + sl * 8;

  f32x4 acc[MF][NF];
#pragma unroll
  for (int mf = 0; mf < MF; ++mf)
#pragma unroll
    for (int nf = 0; nf < NF; ++nf) acc[mf][nf] = (f32x4)0.f;

  short8 ra[AC], rb[NF];
#pragma unroll
  for (int j = 0; j < AC; ++j)
    ra[j] = *(const short8*)(Ablk + (size_t)(j * 64 + r0) * GK + gcol);
#pragma unroll
  for (int j = 0; j < NF; ++j)
    rb[j] = *(const short8*)(Bblk + (size_t)(j * 64 + r0) * GK + gcol);
#pragma unroll
  for (int j = 0; j < AC; ++j) *(short8*)&As[0][j * 4096 + ldsb] = ra[j];
#pragma unroll
  for (int j = 0; j < NF; ++j) *(short8*)&Bs[0][j * 4096 + ldsb] = rb[j];
#pragma unroll
  for (int j = 0; j < AC; ++j)
    ra[j] = *(const short8*)(Ablk + (size_t)(j * 64 + r0) * GK + 64 + gcol);
#pragma unroll
  for (int j = 0; j < NF; ++j)
    rb[j] = *(const short8*)(Bblk + (size_t)(j * 64 + r0) * GK + 64 + gcol);
#pragma unroll
  for (int j = 0; j < AC; ++j) *(short8*)&As[1][j * 4096 + ldsb] = ra[j];
#pragma unroll
  for (int j = 0; j < NF; ++j) *(short8*)&Bs[1][j * 4096 + ldsb] = rb[j];
  __syncthreads();

  for (int t = 0; t < NTK; ++t) {
    const bool pre = (t + 2 < NTK);
    if (pre) {
      const int kt = (t + 2) * 64;
#pragma unroll
      for (int j = 0; j < AC; ++j)
        ra[j] = *(const short8*)(Ablk + (size_t)(j * 64 + r0) * GK + kt + gcol);
#pragma unroll
      for (int j = 0; j < NF; ++j)
        rb[j] = *(const short8*)(Bblk + (size_t)(j * 64 + r0) * GK + kt + gcol);
    }
    __builtin_amdgcn_sched_barrier(0);     // pin load issue before compute

    const ushort* cA = As[t & 1];
    const ushort* cB = Bs[t & 1];
    short8 bfr[NF][2];
#pragma unroll
    for (int nf = 0; nf < NF; ++nf) {
      int row = wn * (BN / 4) + nf * 16 + l16;
#pragma unroll
      for (int ks = 0; ks < 2; ++ks)
        bfr[nf][ks] = *(const short8*)&cB[row * 64 + (((ks * 64 + g * 16) ^ ((l16 & 7) << 4)) >> 1)];
    }
#pragma unroll
    for (int p = 0; p < MF / 2; ++p) {
      short8 af[2][2];
#pragma unroll
      for (int mi = 0; mi < 2; ++mi) {
        int row = wm * (BM / 2) + (2 * p + mi) * 16 + l16;
#pragma unroll
        for (int ks = 0; ks < 2; ++ks)
          af[mi][ks] = *(const short8*)&cA[row * 64 + (((ks * 64 + g * 16) ^ ((l16 & 7) << 4)) >> 1)];
      }
      __builtin_amdgcn_s_setprio(1);
#pragma unroll
      for (int mi = 0; mi < 2; ++mi)
#pragma unroll
        for (int nf = 0; nf < NF; ++nf)
#pragma unroll
          for (int ks = 0; ks < 2; ++ks)
            acc[2 * p + mi][nf] = __builtin_amdgcn_mfma_f32_16x16x32_bf16(
                af[mi][ks], bfr[nf][ks], acc[2 * p + mi][nf], 0, 0, 0);
      __builtin_amdgcn_s_setprio(0);
    }

    __syncthreads();                       // readers done + vmcnt drain
    if (pre) {
      ushort* nA = (ushort*)As[t & 1];
      ushort* nB = (ushort*)Bs[t & 1];
#pragma unroll
      for (int j = 0; j < AC; ++j) *(short8*)&nA[j * 4096 + ldsb] = ra[j];
#pragma unroll
      for (int j = 0; j < NF; ++j) *(short8*)&nB[j * 4096 + ldsb] = rb[j];
    }
  }

#pragma unroll
  for (int mf = 0; mf < MF; ++mf)
#pragma unroll
    for (int nf = 0; nf < NF; ++nf)
#pragma unroll
      for (int i = 0; i < 4; ++i) {
        int row = m0 + wm * (BM / 2) + mf * 16 + g * 4 + i;
        int col = n0 + wn * (BN / 4) + nf * 16 + l16;
        float val = acc[mf][nf][i];
        if (MODE == 0) {
          int which = col >> 11;
          int r = col & 2047;
          int h = r >> 7, dh = r & 127;
          int b = row >> 11, s = row & 2047;
          size_t dst = ((size_t)(b * NH + h) * SEQ + s) * DH + dh;
          ushort* o = (which == 0) ? oq : (which == 1 ? ok : ov);
          o[dst] = f2bf(val);
        } else {
          of[(size_t)row * N + col] = val;
        }
      }
}

// ---------------- RoPE (in-place on head-major bf16 q,k) ----------------
__global__ void rope_kernel(ushort* __restrict__ q, ushort* __restrict__ k,
                            const int* __restrict__ spp) {
  int id = blockIdx.x * blockDim.x + threadIdx.x;   // < B*H*S*64
  int j = id & 63;
  int s = (id >> 6) & (SEQ - 1);
  int bh = id >> 17;
  size_t base = ((size_t)bh * SEQ + s) * DH;
  float pos = (float)(s + spp[0]);
  float ang = pos * __expf(-(float)j * (9.210340371976184f / 64.f)); // 1/10000^(j/64)
  float c = cosf(ang), sn = sinf(ang);
  float q1 = bf2f(q[base + j]), q2 = bf2f(q[base + 64 + j]);
  q[base + j]      = f2bf(q1 * c - q2 * sn);
  q[base + 64 + j] = f2bf(q2 * c + q1 * sn);
  float k1 = bf2f(k[base + j]), k2 = bf2f(k[base + 64 + j]);
  k[base + j]      = f2bf(k1 * c - k2 * sn);
  k[base + 64 + j] = f2bf(k2 * c + k1 * sn);
}

// ---------------- causal flash attention (r18 version, passing) ----------
__global__ __launch_bounds__(256, 2)
void attn_kernel(const ushort* __restrict__ Q, const ushort* __restrict__ K,
                 const ushort* __restrict__ V, ushort* __restrict__ O) {
  __shared__ ushort Ks[2][64 * 128];     // 32 KB
  __shared__ ushort Vt[2][128 * 72];     // 36 KB
  __shared__ ushort Ps[4][16 * 72];      // 9 KB
  const int tid = threadIdx.x;
  const int lane = tid & 63;
  const int w = tid >> 6;
  const int g = lane >> 4, l16 = lane & 15;
  const int h = blockIdx.y, b = blockIdx.z;
  const int bh = b * NH + h;
  const ushort* Qb = Q + (size_t)bh * SEQ * DH;
  const ushort* Kb = K + (size_t)bh * SEQ * DH;
  const ushort* Vb = V + (size_t)bh * SEQ * DH;
  const float scale2 = 0.08838834764831845f * 1.4426950408889634f;  // /sqrt(128) * log2e
  const float THR2   = 11.541560327111708f;                          // 8 * log2e

  const int vkv = (tid >> 3) * 2;       // 0..62
  const int vd0 = (tid & 7) * 16;       // 0..112
  const int vmask = (tid & 7) << 3;     // XOR swizzle ((d>>4)&7)<<3

  for (int pass = 0; pass < 2; ++pass) {
    const int qt = pass == 0 ? (31 - (int)blockIdx.x) : (int)blockIdx.x;
    const int q0 = qt * 64;
    const int nkt = qt + 1;

    short8 qf[4];
    {
      const ushort* qrow = Qb + (size_t)(q0 + w * 16 + l16) * DH;
#pragma unroll
      for (int ks = 0; ks < 4; ++ks) qf[ks] = *(const short8*)(qrow + ks * 32 + g * 8);
    }
    f32x4 oacc[8];
#pragma unroll
    for (int i = 0; i < 8; ++i) oacc[i] = (f32x4)0.f;
    float m_i[4], l_i[4];                 // l_i is a PER-LANE partial until epilogue
#pragma unroll
    for (int i = 0; i < 4; ++i) { m_i[i] = -INFINITY; l_i[i] = 0.f; }

#pragma unroll
    for (int it = 0; it < 4; ++it) {
      int ci = it * 256 + tid;
      int row = ci >> 4;
      int cb = ((ci & 15) * 16) ^ ((row & 7) << 4);
      async16(Kb + (size_t)row * DH + (cb >> 1), &Ks[0][ci * 8]);
    }
    {
      short8 vr[4];
      vr[0] = *(const short8*)(Vb + (size_t)vkv * DH + vd0);
      vr[1] = *(const short8*)(Vb + (size_t)vkv * DH + vd0 + 8);
      vr[2] = *(const short8*)(Vb + (size_t)(vkv + 1) * DH + vd0);
      vr[3] = *(const short8*)(Vb + (size_t)(vkv + 1) * DH + vd0 + 8);
#pragma unroll
      for (int j = 0; j < 16; ++j) {
        int d = vd0 + j;
        const ushort* a = (const ushort*)&vr[j >> 3];
        const ushort* c = (const ushort*)&vr[2 + (j >> 3)];
        unsigned val = (unsigned)a[j & 7] | ((unsigned)c[j & 7] << 16);
        *(unsigned*)&Vt[0][d * 72 + (vkv ^ vmask)] = val;
      }
    }
    __syncthreads();

    int cur = 0;
    for (int t = 0; t < nkt; ++t) {
      const int k0 = t * 64;
      const int nxt = cur ^ 1;
      const bool pre = (t + 1 < nkt);
      short8 vr[4];
      if (pre) {
        const int kn = (t + 1) * 64;
#pragma unroll
        for (int it = 0; it < 4; ++it) {
          int ci = it * 256 + tid;
          int row = ci >> 4;
          int cb = ((ci & 15) * 16) ^ ((row & 7) << 4);
          async16(Kb + (size_t)(kn + row) * DH + (cb >> 1), &Ks[nxt][ci * 8]);
        }
        vr[0] = *(const short8*)(Vb + (size_t)(kn + vkv) * DH + vd0);
        vr[1] = *(const short8*)(Vb + (size_t)(kn + vkv) * DH + vd0 + 8);
        vr[2] = *(const short8*)(Vb + (size_t)(kn + vkv + 1) * DH + vd0);
        vr[3] = *(const short8*)(Vb + (size_t)(kn + vkv + 1) * DH + vd0 + 8);
      }

      // ---- QK^T : S[16 q][64 keys] per wave ----
      f32x4 sacc[4];
#pragma unroll
      for (int nf = 0; nf < 4; ++nf) sacc[nf] = (f32x4)0.f;
      __builtin_amdgcn_s_setprio(1);
#pragma unroll
      for (int nf = 0; nf < 4; ++nf) {
        int row = nf * 16 + l16;
#pragma unroll
        for (int ks = 0; ks < 4; ++ks) {
          int cb = (ks * 64 + g * 16) ^ ((l16 & 7) << 4);
          short8 kf = *(const short8*)&Ks[cur][row * 128 + (cb >> 1)];
          sacc[nf] = __builtin_amdgcn_mfma_f32_16x16x32_bf16(qf[ks], kf, sacc[nf], 0, 0, 0);
        }
      }
      __builtin_amdgcn_s_setprio(0);

      // ---- online softmax, exp2 domain (diag-only mask; defer-max) ----
      float pv[4][4], mxr[4];
#pragma unroll
      for (int i = 0; i < 4; ++i)
#pragma unroll
        for (int nf = 0; nf < 4; ++nf) pv[i][nf] = sacc[nf][i] * scale2;
      if (t == nkt - 1) {                  // diagonal tile: apply causal mask
#pragma unroll
        for (int i = 0; i < 4; ++i) {
          int qrow = q0 + w * 16 + g * 4 + i;
#pragma unroll
          for (int nf = 0; nf < 4; ++nf)
            if (k0 + nf * 16 + l16 > qrow) pv[i][nf] = -INFINITY;
        }
      }
#pragma unroll
      for (int i = 0; i < 4; ++i) {
        float mx = fmaxf(fmaxf(pv[i][0], pv[i][1]), fmaxf(pv[i][2], pv[i][3]));
#pragma unroll
        for (int d = 1; d < 16; d <<= 1) mx = fmaxf(mx, __shfl_xor(mx, d, 64));
        mxr[i] = mx;
      }
      int need = 0;
#pragma unroll
      for (int i = 0; i < 4; ++i) need |= (mxr[i] > m_i[i] + THR2) ? 1 : 0;
      if (__any(need)) {
#pragma unroll
        for (int i = 0; i < 4; ++i) {
          float mnew = fmaxf(m_i[i], mxr[i]);
          float alpha = exp2f(m_i[i] - mnew);
          l_i[i] *= alpha;
          m_i[i] = mnew;
#pragma unroll
          for (int nf2 = 0; nf2 < 8; ++nf2) oacc[nf2][i] *= alpha;
        }
      }
#pragma unroll
      for (int i = 0; i < 4; ++i) {
        float p[4];
#pragma unroll
        for (int nf = 0; nf < 4; ++nf) p[nf] = exp2f(pv[i][nf] - m_i[i]);
        l_i[i] += (p[0] + p[1]) + (p[2] + p[3]);   // per-lane partial, no shuffle
#pragma unroll
        for (int nf = 0; nf < 4; ++nf)
          Ps[w][(g * 4 + i) * 72 + nf * 16 + l16] = f2bf(p[nf]);
      }
      __asm__ volatile("s_waitcnt lgkmcnt(0)" ::: "memory");
      __builtin_amdgcn_sched_barrier(0);

      // ---- PV: O[16 q][128 dh] += P[16][64] @ V[64][128] ----
      __builtin_amdgcn_s_setprio(1);
#pragma unroll
      for (int kvh = 0; kvh < 2; ++kvh) {
        short8 pa = *(const short8*)&Ps[w][l16 * 72 + kvh * 32 + g * 8];
#pragma unroll
        for (int nf2 = 0; nf2 < 8; ++nf2) {
          int cb = (kvh * 32 + g * 8) ^ (nf2 * 8);
          short8 vf = *(const short8*)&Vt[cur][(nf2 * 16 + l16) * 72 + cb];
          oacc[nf2] = __builtin_amdgcn_mfma_f32_16x16x32_bf16(pa, vf, oacc[nf2], 0, 0, 0);
        }
      }
      __builtin_amdgcn_s_setprio(0);

      if (pre) {
#pragma unroll
        for (int j = 0; j < 16; ++j) {
          int d = vd0 + j;
          const ushort* a = (const ushort*)&vr[j >> 3];
          const ushort* c = (const ushort*)&vr[2 + (j >> 3)];
          unsigned val = (unsigned)a[j & 7] | ((unsigned)c[j & 7] << 16);
          *(unsigned*)&Vt[nxt][d * 72 + (vkv ^ vmask)] = val;
        }
      }
      __syncthreads();
      cur = nxt;
    }

    // ---- epilogue: single l-reduction across the 16-lane row group ----
#pragma unroll
    for (int i = 0; i < 4; ++i) {
      float sum = l_i[i];
#pragma unroll
      for (int d = 1; d < 16; d <<= 1) sum += __shfl_xor(sum, d, 64);
      float inv = 1.f / sum;
      int row = q0 + w * 16 + g * 4 + i;
      size_t obase = ((size_t)b * SEQ + row) * DMODEL + h * DH;
#pragma unroll
      for (int nf2 = 0; nf2 < 8; ++nf2)
        O[obase + nf2 * 16 + l16] = f2bf(oacc[nf2][i] * inv);
    }
  }
}

// ---------------- launch ----------------
extern "C" void kernel_launch(void* const* d_in, const int* in_sizes, int n_in,
                              void* d_out, int out_size, void* d_ws, size_t ws_size,
                              hipStream_t stream) {
  const float* x    = (const float*)d_in[0];
  const float* wqkv = (const float*)d_in[1];
  const float* wout = (const float*)d_in[2];
  const int*   spp  = (const int*)d_in[3];
  float* out = (float*)d_out;

  ushort* ws = (ushort*)d_ws;
  ushort* xb  = ws;                       // 8,388,608
  ushort* wqb = xb + 8388608;             // 12,582,912
  ushort* wob = wqb + 12582912;           // 4,194,304
  ushort* q   = wob + 4194304;            // 8,388,608
  ushort* k   = q + 8388608;
  ushort* v   = k + 8388608;
  ushort* ao  = v + 8388608;              // 8,388,608

  cast3_kernel<<<2048, 256, 0, stream>>>(x, wqkv, wout, xb, wqb, wob);

  // GEMM1: BM=256, BN=192 -> grid 32x16 = 512 blocks = exactly 2 rounds
  gemmk<0, 32, 256, 192><<<dim3(6144 / 192, 4096 / 256, 1), 512, 0, stream>>>(
      xb, wqb, 6144, q, k, v, nullptr);

  rope_kernel<<<4194304 / 256, 256, 0, stream>>>(q, k, spp);

  attn_kernel<<<dim3(16, NH, 2), 256, 0, stream>>>(q, k, v, ao);

  // GEMM2: BM=128, BN=256 -> grid 8x32 = 256 blocks = exactly 1 round, full K;
  // wave tile 64x64 (0.5 KB/MFMA -> ~45% LDS ceiling vs 31% at 128x32)
  gemmk<1, 32, 128, 256><<<dim3(2048 / 256, 4096 / 128, 1), 512, 0, stream>>>(
      ao, wob, 2048, nullptr, nullptr, nullptr, out);
}

// Round 21
// 258.845 us; speedup vs baseline: 1.0671x; 1.0025x over previous
//
#include <hip/hip_runtime.h>

typedef unsigned short ushort;
typedef __attribute__((ext_vector_type(8))) short short8;
typedef __attribute__((ext_vector_type(4))) float f32x4;

#define NH 16
#define DH 128
#define SEQ 2048
#define DMODEL 2048
#define GK 2048   // K dim for both GEMMs

__device__ __forceinline__ ushort f2bf(float f) {
  union { float f; unsigned u; } v; v.f = f;
  unsigned u = v.u;
  unsigned r = (u + 0x7fffu + ((u >> 16) & 1u)) >> 16;
  return (ushort)r;
}
__device__ __forceinline__ float bf2f(ushort h) {
  union { unsigned u; float f; } v; v.u = ((unsigned)h) << 16; return v.f;
}

__device__ __forceinline__ void async16(const ushort* g, ushort* l) {
  __builtin_amdgcn_global_load_lds(
      (const __attribute__((address_space(1))) unsigned*)g,
      (__attribute__((address_space(3))) unsigned*)l, 16, 0, 0);
}

// ---------------- fused cast fp32 -> bf16 for x, wqkv, wout ----------------
#define NX  2097152   // x      f4 count
#define NWQ 3145728   // wqkv   f4 count
#define NWO 1048576   // wout   f4 count
__global__ void cast3_kernel(const float* __restrict__ x, const float* __restrict__ wq,
                             const float* __restrict__ wo, ushort* __restrict__ xb,
                             ushort* __restrict__ wqb, ushort* __restrict__ wob) {
  int i = blockIdx.x * blockDim.x + threadIdx.x;
  int stride = gridDim.x * blockDim.x;
  for (; i < NX + NWQ + NWO; i += stride) {
    const float* s; ushort* d; int j;
    if (i < NX)            { s = x;  d = xb;  j = i; }
    else if (i < NX + NWQ) { s = wq; d = wqb; j = i - NX; }
    else                   { s = wo; d = wob; j = i - NX - NWQ; }
    float4 v = ((const float4*)s)[j];
    unsigned long long p = (unsigned long long)f2bf(v.x)
                         | ((unsigned long long)f2bf(v.y) << 16)
                         | ((unsigned long long)f2bf(v.z) << 32)
                         | ((unsigned long long)f2bf(v.w) << 48);
    ((unsigned long long*)d)[j] = p;
  }
}

// ---------------- BMxBN GEMM, reg-staged 2-tile-deep pipeline ----------------
// 512 threads = 8 waves arranged WM(M) x (8/WM)(N); wave tile (BM/WM) x (BN*WM/8).
// BK=64, 2 LDS slots, global->VGPR->LDS staging, 1 barrier/K-tile.
// GEMM1 uses WM=4 (wave 64x96: 20 KB frag-reads / 48 MFMA -> 55% LDS ceiling
// vs 51% at 2M x 4N).  GEMM2 keeps WM=2 (identical to r20's passing config).
template<int MODE, int NTK, int BM, int BN, int WM>
__global__ __launch_bounds__(512, 1)
void gemmk(const ushort* __restrict__ A, const ushort* __restrict__ B, int N,
           ushort* __restrict__ oq, ushort* __restrict__ ok, ushort* __restrict__ ov,
           float* __restrict__ of) {
  constexpr int WNW = 8 / WM;              // waves in N
  constexpr int MF = BM / (WM * 16);       // M frags / wave
  constexpr int NF = BN / (WNW * 16);      // N frags / wave
  constexpr int AC = BM / 64;              // A staging chunks / thread
  constexpr int BC = BN / 64;              // B staging chunks / thread
  __shared__ ushort As[2][BM * 64];
  __shared__ ushort Bs[2][BN * 64];
  const int tid = threadIdx.x;
  const int lane = tid & 63;
  const int w = tid >> 6;
  const int wm = w / WNW, wn = w % WNW;
  const int g = lane >> 4, l16 = lane & 15;
  const int m0 = blockIdx.y * BM;
  const int n0 = blockIdx.x * BN;
  const ushort* Ablk = A + (size_t)m0 * GK;
  const ushort* Bblk = B + (size_t)n0 * GK;

  const int r0 = tid >> 3, sl = tid & 7;
  const int gcol = ((sl * 16) ^ ((r0 & 7) << 4)) >> 1;
  const int ldsb = r0 * 64 + sl * 8;

  f32x4 acc[MF][NF];
#pragma unroll
  for (int mf = 0; mf < MF; ++mf)
#pragma unroll
    for (int nf = 0; nf < NF; ++nf) acc[mf][nf] = (f32x4)0.f;

  short8 ra[AC], rb[BC];
#pragma unroll
  for (int j = 0; j < AC; ++j)
    ra[j] = *(const short8*)(Ablk + (size_t)(j * 64 + r0) * GK + gcol);
#pragma unroll
  for (int j = 0; j < BC; ++j)
    rb[j] = *(const short8*)(Bblk + (size_t)(j * 64 + r0) * GK + gcol);
#pragma unroll
  for (int j = 0; j < AC; ++j) *(short8*)&As[0][j * 4096 + ldsb] = ra[j];
#pragma unroll
  for (int j = 0; j < BC; ++j) *(short8*)&Bs[0][j * 4096 + ldsb] = rb[j];
#pragma unroll
  for (int j = 0; j < AC; ++j)
    ra[j] = *(const short8*)(Ablk + (size_t)(j * 64 + r0) * GK + 64 + gcol);
#pragma unroll
  for (int j = 0; j < BC; ++j)
    rb[j] = *(const short8*)(Bblk + (size_t)(j * 64 + r0) * GK + 64 + gcol);
#pragma unroll
  for (int j = 0; j < AC; ++j) *(short8*)&As[1][j * 4096 + ldsb] = ra[j];
#pragma unroll
  for (int j = 0; j < BC; ++j) *(short8*)&Bs[1][j * 4096 + ldsb] = rb[j];
  __syncthreads();

  for (int t = 0; t < NTK; ++t) {
    const bool pre = (t + 2 < NTK);
    if (pre) {
      const int kt = (t + 2) * 64;
#pragma unroll
      for (int j = 0; j < AC; ++j)
        ra[j] = *(const short8*)(Ablk + (size_t)(j * 64 + r0) * GK + kt + gcol);
#pragma unroll
      for (int j = 0; j < BC; ++j)
        rb[j] = *(const short8*)(Bblk + (size_t)(j * 64 + r0) * GK + kt + gcol);
    }
    __builtin_amdgcn_sched_barrier(0);     // pin load issue before compute

    const ushort* cA = As[t & 1];
    const ushort* cB = Bs[t & 1];
    short8 bfr[NF][2];
#pragma unroll
    for (int nf = 0; nf < NF; ++nf) {
      int row = wn * (BN / WNW) + nf * 16 + l16;
#pragma unroll
      for (int ks = 0; ks < 2; ++ks)
        bfr[nf][ks] = *(const short8*)&cB[row * 64 + (((ks * 64 + g * 16) ^ ((l16 & 7) << 4)) >> 1)];
    }
#pragma unroll
    for (int p = 0; p < MF / 2; ++p) {
      short8 af[2][2];
#pragma unroll
      for (int mi = 0; mi < 2; ++mi) {
        int row = wm * (BM / WM) + (2 * p + mi) * 16 + l16;
#pragma unroll
        for (int ks = 0; ks < 2; ++ks)
          af[mi][ks] = *(const short8*)&cA[row * 64 + (((ks * 64 + g * 16) ^ ((l16 & 7) << 4)) >> 1)];
      }
      __builtin_amdgcn_s_setprio(1);
#pragma unroll
      for (int mi = 0; mi < 2; ++mi)
#pragma unroll
        for (int nf = 0; nf < NF; ++nf)
#pragma unroll
          for (int ks = 0; ks < 2; ++ks)
            acc[2 * p + mi][nf] = __builtin_amdgcn_mfma_f32_16x16x32_bf16(
                af[mi][ks], bfr[nf][ks], acc[2 * p + mi][nf], 0, 0, 0);
      __builtin_amdgcn_s_setprio(0);
    }

    __syncthreads();                       // readers done + vmcnt drain
    if (pre) {
      ushort* nA = (ushort*)As[t & 1];
      ushort* nB = (ushort*)Bs[t & 1];
#pragma unroll
      for (int j = 0; j < AC; ++j) *(short8*)&nA[j * 4096 + ldsb] = ra[j];
#pragma unroll
      for (int j = 0; j < BC; ++j) *(short8*)&nB[j * 4096 + ldsb] = rb[j];
    }
  }

#pragma unroll
  for (int mf = 0; mf < MF; ++mf)
#pragma unroll
    for (int nf = 0; nf < NF; ++nf)
#pragma unroll
      for (int i = 0; i < 4; ++i) {
        int row = m0 + wm * (BM / WM) + mf * 16 + g * 4 + i;
        int col = n0 + wn * (BN / WNW) + nf * 16 + l16;
        float val = acc[mf][nf][i];
        if (MODE == 0) {
          int which = col >> 11;
          int r = col & 2047;
          int h = r >> 7, dh = r & 127;
          int b = row >> 11, s = row & 2047;
          size_t dst = ((size_t)(b * NH + h) * SEQ + s) * DH + dh;
          ushort* o = (which == 0) ? oq : (which == 1 ? ok : ov);
          o[dst] = f2bf(val);
        } else {
          of[(size_t)row * N + col] = val;
        }
      }
}

// ---------------- RoPE (in-place on head-major bf16 q,k) ----------------
__global__ void rope_kernel(ushort* __restrict__ q, ushort* __restrict__ k,
                            const int* __restrict__ spp) {
  int id = blockIdx.x * blockDim.x + threadIdx.x;   // < B*H*S*64
  int j = id & 63;
  int s = (id >> 6) & (SEQ - 1);
  int bh = id >> 17;
  size_t base = ((size_t)bh * SEQ + s) * DH;
  float pos = (float)(s + spp[0]);
  float ang = pos * __expf(-(float)j * (9.210340371976184f / 64.f)); // 1/10000^(j/64)
  float c = cosf(ang), sn = sinf(ang);
  float q1 = bf2f(q[base + j]), q2 = bf2f(q[base + 64 + j]);
  q[base + j]      = f2bf(q1 * c - q2 * sn);
  q[base + 64 + j] = f2bf(q2 * c + q1 * sn);
  float k1 = bf2f(k[base + j]), k2 = bf2f(k[base + 64 + j]);
  k[base + j]      = f2bf(k1 * c - k2 * sn);
  k[base + 64 + j] = f2bf(k2 * c + k1 * sn);
}

// ---------------- causal flash attention (r18 version, passing) ----------
__global__ __launch_bounds__(256, 2)
void attn_kernel(const ushort* __restrict__ Q, const ushort* __restrict__ K,
                 const ushort* __restrict__ V, ushort* __restrict__ O) {
  __shared__ ushort Ks[2][64 * 128];     // 32 KB
  __shared__ ushort Vt[2][128 * 72];     // 36 KB
  __shared__ ushort Ps[4][16 * 72];      // 9 KB
  const int tid = threadIdx.x;
  const int lane = tid & 63;
  const int w = tid >> 6;
  const int g = lane >> 4, l16 = lane & 15;
  const int h = blockIdx.y, b = blockIdx.z;
  const int bh = b * NH + h;
  const ushort* Qb = Q + (size_t)bh * SEQ * DH;
  const ushort* Kb = K + (size_t)bh * SEQ * DH;
  const ushort* Vb = V + (size_t)bh * SEQ * DH;
  const float scale2 = 0.08838834764831845f * 1.4426950408889634f;  // /sqrt(128) * log2e
  const float THR2   = 11.541560327111708f;                          // 8 * log2e

  const int vkv = (tid >> 3) * 2;       // 0..62
  const int vd0 = (tid & 7) * 16;       // 0..112
  const int vmask = (tid & 7) << 3;     // XOR swizzle ((d>>4)&7)<<3

  for (int pass = 0; pass < 2; ++pass) {
    const int qt = pass == 0 ? (31 - (int)blockIdx.x) : (int)blockIdx.x;
    const int q0 = qt * 64;
    const int nkt = qt + 1;

    short8 qf[4];
    {
      const ushort* qrow = Qb + (size_t)(q0 + w * 16 + l16) * DH;
#pragma unroll
      for (int ks = 0; ks < 4; ++ks) qf[ks] = *(const short8*)(qrow + ks * 32 + g * 8);
    }
    f32x4 oacc[8];
#pragma unroll
    for (int i = 0; i < 8; ++i) oacc[i] = (f32x4)0.f;
    float m_i[4], l_i[4];                 // l_i is a PER-LANE partial until epilogue
#pragma unroll
    for (int i = 0; i < 4; ++i) { m_i[i] = -INFINITY; l_i[i] = 0.f; }

#pragma unroll
    for (int it = 0; it < 4; ++it) {
      int ci = it * 256 + tid;
      int row = ci >> 4;
      int cb = ((ci & 15) * 16) ^ ((row & 7) << 4);
      async16(Kb + (size_t)row * DH + (cb >> 1), &Ks[0][ci * 8]);
    }
    {
      short8 vr[4];
      vr[0] = *(const short8*)(Vb + (size_t)vkv * DH + vd0);
      vr[1] = *(const short8*)(Vb + (size_t)vkv * DH + vd0 + 8);
      vr[2] = *(const short8*)(Vb + (size_t)(vkv + 1) * DH + vd0);
      vr[3] = *(const short8*)(Vb + (size_t)(vkv + 1) * DH + vd0 + 8);
#pragma unroll
      for (int j = 0; j < 16; ++j) {
        int d = vd0 + j;
        const ushort* a = (const ushort*)&vr[j >> 3];
        const ushort* c = (const ushort*)&vr[2 + (j >> 3)];
        unsigned val = (unsigned)a[j & 7] | ((unsigned)c[j & 7] << 16);
        *(unsigned*)&Vt[0][d * 72 + (vkv ^ vmask)] = val;
      }
    }
    __syncthreads();

    int cur = 0;
    for (int t = 0; t < nkt; ++t) {
      const int k0 = t * 64;
      const int nxt = cur ^ 1;
      const bool pre = (t + 1 < nkt);
      short8 vr[4];
      if (pre) {
        const int kn = (t + 1) * 64;
#pragma unroll
        for (int it = 0; it < 4; ++it) {
          int ci = it * 256 + tid;
          int row = ci >> 4;
          int cb = ((ci & 15) * 16) ^ ((row & 7) << 4);
          async16(Kb + (size_t)(kn + row) * DH + (cb >> 1), &Ks[nxt][ci * 8]);
        }
        vr[0] = *(const short8*)(Vb + (size_t)(kn + vkv) * DH + vd0);
        vr[1] = *(const short8*)(Vb + (size_t)(kn + vkv) * DH + vd0 + 8);
        vr[2] = *(const short8*)(Vb + (size_t)(kn + vkv + 1) * DH + vd0);
        vr[3] = *(const short8*)(Vb + (size_t)(kn + vkv + 1) * DH + vd0 + 8);
      }

      // ---- QK^T : S[16 q][64 keys] per wave ----
      f32x4 sacc[4];
#pragma unroll
      for (int nf = 0; nf < 4; ++nf) sacc[nf] = (f32x4)0.f;
      __builtin_amdgcn_s_setprio(1);
#pragma unroll
      for (int nf = 0; nf < 4; ++nf) {
        int row = nf * 16 + l16;
#pragma unroll
        for (int ks = 0; ks < 4; ++ks) {
          int cb = (ks * 64 + g * 16) ^ ((l16 & 7) << 4);
          short8 kf = *(const short8*)&Ks[cur][row * 128 + (cb >> 1)];
          sacc[nf] = __builtin_amdgcn_mfma_f32_16x16x32_bf16(qf[ks], kf, sacc[nf], 0, 0, 0);
        }
      }
      __builtin_amdgcn_s_setprio(0);

      // ---- online softmax, exp2 domain (diag-only mask; defer-max) ----
      float pv[4][4], mxr[4];
#pragma unroll
      for (int i = 0; i < 4; ++i)
#pragma unroll
        for (int nf = 0; nf < 4; ++nf) pv[i][nf] = sacc[nf][i] * scale2;
      if (t == nkt - 1) {                  // diagonal tile: apply causal mask
#pragma unroll
        for (int i = 0; i < 4; ++i) {
          int qrow = q0 + w * 16 + g * 4 + i;
#pragma unroll
          for (int nf = 0; nf < 4; ++nf)
            if (k0 + nf * 16 + l16 > qrow) pv[i][nf] = -INFINITY;
        }
      }
#pragma unroll
      for (int i = 0; i < 4; ++i) {
        float mx = fmaxf(fmaxf(pv[i][0], pv[i][1]), fmaxf(pv[i][2], pv[i][3]));
#pragma unroll
        for (int d = 1; d < 16; d <<= 1) mx = fmaxf(mx, __shfl_xor(mx, d, 64));
        mxr[i] = mx;
      }
      int need = 0;
#pragma unroll
      for (int i = 0; i < 4; ++i) need |= (mxr[i] > m_i[i] + THR2) ? 1 : 0;
      if (__any(need)) {
#pragma unroll
        for (int i = 0; i < 4; ++i) {
          float mnew = fmaxf(m_i[i], mxr[i]);
          float alpha = exp2f(m_i[i] - mnew);
          l_i[i] *= alpha;
          m_i[i] = mnew;
#pragma unroll
          for (int nf2 = 0; nf2 < 8; ++nf2) oacc[nf2][i] *= alpha;
        }
      }
#pragma unroll
      for (int i = 0; i < 4; ++i) {
        float p[4];
#pragma unroll
        for (int nf = 0; nf < 4; ++nf) p[nf] = exp2f(pv[i][nf] - m_i[i]);
        l_i[i] += (p[0] + p[1]) + (p[2] + p[3]);   // per-lane partial, no shuffle
#pragma unroll
        for (int nf = 0; nf < 4; ++nf)
          Ps[w][(g * 4 + i) * 72 + nf * 16 + l16] = f2bf(p[nf]);
      }
      __asm__ volatile("s_waitcnt lgkmcnt(0)" ::: "memory");
      __builtin_amdgcn_sched_barrier(0);

      // ---- PV: O[16 q][128 dh] += P[16][64] @ V[64][128] ----
      __builtin_amdgcn_s_setprio(1);
#pragma unroll
      for (int kvh = 0; kvh < 2; ++kvh) {
        short8 pa = *(const short8*)&Ps[w][l16 * 72 + kvh * 32 + g * 8];
#pragma unroll
        for (int nf2 = 0; nf2 < 8; ++nf2) {
          int cb = (kvh * 32 + g * 8) ^ (nf2 * 8);
          short8 vf = *(const short8*)&Vt[cur][(nf2 * 16 + l16) * 72 + cb];
          oacc[nf2] = __builtin_amdgcn_mfma_f32_16x16x32_bf16(pa, vf, oacc[nf2], 0, 0, 0);
        }
      }
      __builtin_amdgcn_s_setprio(0);

      if (pre) {
#pragma unroll
        for (int j = 0; j < 16; ++j) {
          int d = vd0 + j;
          const ushort* a = (const ushort*)&vr[j >> 3];
          const ushort* c = (const ushort*)&vr[2 + (j >> 3)];
          unsigned val = (unsigned)a[j & 7] | ((unsigned)c[j & 7] << 16);
          *(unsigned*)&Vt[nxt][d * 72 + (vkv ^ vmask)] = val;
        }
      }
      __syncthreads();
      cur = nxt;
    }

    // ---- epilogue: single l-reduction across the 16-lane row group ----
#pragma unroll
    for (int i = 0; i < 4; ++i) {
      float sum = l_i[i];
#pragma unroll
      for (int d = 1; d < 16; d <<= 1) sum += __shfl_xor(sum, d, 64);
      float inv = 1.f / sum;
      int row = q0 + w * 16 + g * 4 + i;
      size_t obase = ((size_t)b * SEQ + row) * DMODEL + h * DH;
#pragma unroll
      for (int nf2 = 0; nf2 < 8; ++nf2)
        O[obase + nf2 * 16 + l16] = f2bf(oacc[nf2][i] * inv);
    }
  }
}

// ---------------- launch ----------------
extern "C" void kernel_launch(void* const* d_in, const int* in_sizes, int n_in,
                              void* d_out, int out_size, void* d_ws, size_t ws_size,
                              hipStream_t stream) {
  const float* x    = (const float*)d_in[0];
  const float* wqkv = (const float*)d_in[1];
  const float* wout = (const float*)d_in[2];
  const int*   spp  = (const int*)d_in[3];
  float* out = (float*)d_out;

  ushort* ws = (ushort*)d_ws;
  ushort* xb  = ws;                       // 8,388,608
  ushort* wqb = xb + 8388608;             // 12,582,912
  ushort* wob = wqb + 12582912;           // 4,194,304
  ushort* q   = wob + 4194304;            // 8,388,608
  ushort* k   = q + 8388608;
  ushort* v   = k + 8388608;
  ushort* ao  = v + 8388608;              // 8,388,608

  cast3_kernel<<<2048, 256, 0, stream>>>(x, wqkv, wout, xb, wqb, wob);

  // GEMM1: BM=256, BN=192, 4M x 2N waves (wave tile 64x96, 55% LDS ceiling);
  // grid 32x16 = 512 blocks = exactly 2 rounds on 256 CUs
  gemmk<0, 32, 256, 192, 4><<<dim3(6144 / 192, 4096 / 256, 1), 512, 0, stream>>>(
      xb, wqb, 6144, q, k, v, nullptr);

  rope_kernel<<<4194304 / 256, 256, 0, stream>>>(q, k, spp);

  attn_kernel<<<dim3(16, NH, 2), 256, 0, stream>>>(q, k, v, ao);

  // GEMM2: BM=128, BN=256, 2M x 4N (identical to r20's passing config);
  // grid 8x32 = 256 blocks = exactly 1 round, full K
  gemmk<1, 32, 128, 256, 2><<<dim3(2048 / 256, 4096 / 128, 1), 512, 0, stream>>>(
      ao, wob, 2048, nullptr, nullptr, nullptr, out);
}

// Round 22
// 252.676 us; speedup vs baseline: 1.0931x; 1.0244x over previous
//
#include <hip/hip_runtime.h>

typedef unsigned short ushort;
typedef __attribute__((ext_vector_type(8))) short short8;
typedef __attribute__((ext_vector_type(4))) float f32x4;

#define NH 16
#define DH 128
#define SEQ 2048
#define DMODEL 2048
#define GK 2048   // K dim for both GEMMs

__device__ __forceinline__ ushort f2bf(float f) {
  union { float f; unsigned u; } v; v.f = f;
  unsigned u = v.u;
  unsigned r = (u + 0x7fffu + ((u >> 16) & 1u)) >> 16;
  return (ushort)r;
}
__device__ __forceinline__ float bf2f(ushort h) {
  union { unsigned u; float f; } v; v.u = ((unsigned)h) << 16; return v.f;
}

__device__ __forceinline__ void async16(const ushort* g, ushort* l) {
  __builtin_amdgcn_global_load_lds(
      (const __attribute__((address_space(1))) unsigned*)g,
      (__attribute__((address_space(3))) unsigned*)l, 16, 0, 0);
}

// ---------------- fused cast fp32 -> bf16 for x, wqkv, wout ----------------
#define NX  2097152   // x      f4 count
#define NWQ 3145728   // wqkv   f4 count
#define NWO 1048576   // wout   f4 count
__global__ void cast3_kernel(const float* __restrict__ x, const float* __restrict__ wq,
                             const float* __restrict__ wo, ushort* __restrict__ xb,
                             ushort* __restrict__ wqb, ushort* __restrict__ wob) {
  int i = blockIdx.x * blockDim.x + threadIdx.x;
  int stride = gridDim.x * blockDim.x;
  for (; i < NX + NWQ + NWO; i += stride) {
    const float* s; ushort* d; int j;
    if (i < NX)            { s = x;  d = xb;  j = i; }
    else if (i < NX + NWQ) { s = wq; d = wqb; j = i - NX; }
    else                   { s = wo; d = wob; j = i - NX - NWQ; }
    float4 v = ((const float4*)s)[j];
    unsigned long long p = (unsigned long long)f2bf(v.x)
                         | ((unsigned long long)f2bf(v.y) << 16)
                         | ((unsigned long long)f2bf(v.z) << 32)
                         | ((unsigned long long)f2bf(v.w) << 48);
    ((unsigned long long*)d)[j] = p;
  }
}

// ---------------- BMxBN GEMM, reg-staged 2-tile-deep pipeline ----------------
// 512 threads = 8 waves arranged WM(M) x (8/WM)(N); wave tile (BM/WM) x (BN*WM/8).
// BK=64, 2 LDS slots, global->VGPR->LDS staging, 1 barrier/K-tile.
template<int MODE, int NTK, int BM, int BN, int WM>
__global__ __launch_bounds__(512, 1)
void gemmk(const ushort* __restrict__ A, const ushort* __restrict__ B, int N,
           ushort* __restrict__ oq, ushort* __restrict__ ok, ushort* __restrict__ ov,
           float* __restrict__ of) {
  constexpr int WNW = 8 / WM;              // waves in N
  constexpr int MF = BM / (WM * 16);       // M frags / wave
  constexpr int NF = BN / (WNW * 16);      // N frags / wave
  constexpr int AC = BM / 64;              // A staging chunks / thread
  constexpr int BC = BN / 64;              // B staging chunks / thread
  __shared__ ushort As[2][BM * 64];
  __shared__ ushort Bs[2][BN * 64];
  const int tid = threadIdx.x;
  const int lane = tid & 63;
  const int w = tid >> 6;
  const int wm = w / WNW, wn = w % WNW;
  const int g = lane >> 4, l16 = lane & 15;
  const int m0 = blockIdx.y * BM;
  const int n0 = blockIdx.x * BN;
  const ushort* Ablk = A + (size_t)m0 * GK;
  const ushort* Bblk = B + (size_t)n0 * GK;

  const int r0 = tid >> 3, sl = tid & 7;
  const int gcol = ((sl * 16) ^ ((r0 & 7) << 4)) >> 1;
  const int ldsb = r0 * 64 + sl * 8;

  f32x4 acc[MF][NF];
#pragma unroll
  for (int mf = 0; mf < MF; ++mf)
#pragma unroll
    for (int nf = 0; nf < NF; ++nf) acc[mf][nf] = (f32x4)0.f;

  short8 ra[AC], rb[BC];
#pragma unroll
  for (int j = 0; j < AC; ++j)
    ra[j] = *(const short8*)(Ablk + (size_t)(j * 64 + r0) * GK + gcol);
#pragma unroll
  for (int j = 0; j < BC; ++j)
    rb[j] = *(const short8*)(Bblk + (size_t)(j * 64 + r0) * GK + gcol);
#pragma unroll
  for (int j = 0; j < AC; ++j) *(short8*)&As[0][j * 4096 + ldsb] = ra[j];
#pragma unroll
  for (int j = 0; j < BC; ++j) *(short8*)&Bs[0][j * 4096 + ldsb] = rb[j];
#pragma unroll
  for (int j = 0; j < AC; ++j)
    ra[j] = *(const short8*)(Ablk + (size_t)(j * 64 + r0) * GK + 64 + gcol);
#pragma unroll
  for (int j = 0; j < BC; ++j)
    rb[j] = *(const short8*)(Bblk + (size_t)(j * 64 + r0) * GK + 64 + gcol);
#pragma unroll
  for (int j = 0; j < AC; ++j) *(short8*)&As[1][j * 4096 + ldsb] = ra[j];
#pragma unroll
  for (int j = 0; j < BC; ++j) *(short8*)&Bs[1][j * 4096 + ldsb] = rb[j];
  __syncthreads();

  for (int t = 0; t < NTK; ++t) {
    const bool pre = (t + 2 < NTK);
    if (pre) {
      const int kt = (t + 2) * 64;
#pragma unroll
      for (int j = 0; j < AC; ++j)
        ra[j] = *(const short8*)(Ablk + (size_t)(j * 64 + r0) * GK + kt + gcol);
#pragma unroll
      for (int j = 0; j < BC; ++j)
        rb[j] = *(const short8*)(Bblk + (size_t)(j * 64 + r0) * GK + kt + gcol);
    }
    __builtin_amdgcn_sched_barrier(0);     // pin load issue before compute

    const ushort* cA = As[t & 1];
    const ushort* cB = Bs[t & 1];
    short8 bfr[NF][2];
#pragma unroll
    for (int nf = 0; nf < NF; ++nf) {
      int row = wn * (BN / WNW) + nf * 16 + l16;
#pragma unroll
      for (int ks = 0; ks < 2; ++ks)
        bfr[nf][ks] = *(const short8*)&cB[row * 64 + (((ks * 64 + g * 16) ^ ((l16 & 7) << 4)) >> 1)];
    }
#pragma unroll
    for (int p = 0; p < MF / 2; ++p) {
      short8 af[2][2];
#pragma unroll
      for (int mi = 0; mi < 2; ++mi) {
        int row = wm * (BM / WM) + (2 * p + mi) * 16 + l16;
#pragma unroll
        for (int ks = 0; ks < 2; ++ks)
          af[mi][ks] = *(const short8*)&cA[row * 64 + (((ks * 64 + g * 16) ^ ((l16 & 7) << 4)) >> 1)];
      }
      __builtin_amdgcn_s_setprio(1);
#pragma unroll
      for (int mi = 0; mi < 2; ++mi)
#pragma unroll
        for (int nf = 0; nf < NF; ++nf)
#pragma unroll
          for (int ks = 0; ks < 2; ++ks)
            acc[2 * p + mi][nf] = __builtin_amdgcn_mfma_f32_16x16x32_bf16(
                af[mi][ks], bfr[nf][ks], acc[2 * p + mi][nf], 0, 0, 0);
      __builtin_amdgcn_s_setprio(0);
    }

    __syncthreads();                       // readers done + vmcnt drain
    if (pre) {
      ushort* nA = (ushort*)As[t & 1];
      ushort* nB = (ushort*)Bs[t & 1];
#pragma unroll
      for (int j = 0; j < AC; ++j) *(short8*)&nA[j * 4096 + ldsb] = ra[j];
#pragma unroll
      for (int j = 0; j < BC; ++j) *(short8*)&nB[j * 4096 + ldsb] = rb[j];
    }
  }

#pragma unroll
  for (int mf = 0; mf < MF; ++mf)
#pragma unroll
    for (int nf = 0; nf < NF; ++nf)
#pragma unroll
      for (int i = 0; i < 4; ++i) {
        int row = m0 + wm * (BM / WM) + mf * 16 + g * 4 + i;
        int col = n0 + wn * (BN / WNW) + nf * 16 + l16;
        float val = acc[mf][nf][i];
        if (MODE == 0) {
          int which = col >> 11;
          int r = col & 2047;
          int h = r >> 7, dh = r & 127;
          int b = row >> 11, s = row & 2047;
          size_t dst = ((size_t)(b * NH + h) * SEQ + s) * DH + dh;
          ushort* o = (which == 0) ? oq : (which == 1 ? ok : ov);
          o[dst] = f2bf(val);
        } else {
          of[(size_t)row * N + col] = val;
        }
      }
}

// ---------------- RoPE (in-place on head-major bf16 q,k) ----------------
__global__ void rope_kernel(ushort* __restrict__ q, ushort* __restrict__ k,
                            const int* __restrict__ spp) {
  int id = blockIdx.x * blockDim.x + threadIdx.x;   // < B*H*S*64
  int j = id & 63;
  int s = (id >> 6) & (SEQ - 1);
  int bh = id >> 17;
  size_t base = ((size_t)bh * SEQ + s) * DH;
  float pos = (float)(s + spp[0]);
  float ang = pos * __expf(-(float)j * (9.210340371976184f / 64.f)); // 1/10000^(j/64)
  float c = cosf(ang), sn = sinf(ang);
  float q1 = bf2f(q[base + j]), q2 = bf2f(q[base + 64 + j]);
  q[base + j]      = f2bf(q1 * c - q2 * sn);
  q[base + 64 + j] = f2bf(q2 * c + q1 * sn);
  float k1 = bf2f(k[base + j]), k2 = bf2f(k[base + 64 + j]);
  k[base + j]      = f2bf(k1 * c - k2 * sn);
  k[base + 64 + j] = f2bf(k2 * c + k1 * sn);
}

// ---------------- causal flash attention (r18 core + XCD-pinned blocks) ----
// Flat grid 512.  xcd = fid&7 hosts the 4 (b,h) pairs p = xcd*4 + (s>>4)
// (s = fid>>3), j = s&15 -> all 16 q-blocks of one (b,h) land on ONE XCD:
// its 4 MB KV working set becomes L2-resident and blocks stream tiles in
// near-lockstep (strong temporal reuse).  Per-block work unchanged (uniform
// 33 KV-tiles via the (31-j, j) pass pairing).  Mapping is a perf heuristic
// only -- any XCD assignment is correct.
__global__ __launch_bounds__(256, 2)
void attn_kernel(const ushort* __restrict__ Q, const ushort* __restrict__ K,
                 const ushort* __restrict__ V, ushort* __restrict__ O) {
  __shared__ ushort Ks[2][64 * 128];     // 32 KB
  __shared__ ushort Vt[2][128 * 72];     // 36 KB
  __shared__ ushort Ps[4][16 * 72];      // 9 KB
  const int tid = threadIdx.x;
  const int lane = tid & 63;
  const int w = tid >> 6;
  const int g = lane >> 4, l16 = lane & 15;
  const int fid = (int)blockIdx.x;       // 0..511
  const int xcd = fid & 7;
  const int s8 = fid >> 3;               // 0..63
  const int pl = s8 >> 4;                // 0..3
  const int jq = s8 & 15;                // 0..15
  const int p = xcd * 4 + pl;            // 0..31 : (b,h) pair
  const int b = p >> 4, h = p & 15;
  const int bh = b * NH + h;
  const ushort* Qb = Q + (size_t)bh * SEQ * DH;
  const ushort* Kb = K + (size_t)bh * SEQ * DH;
  const ushort* Vb = V + (size_t)bh * SEQ * DH;
  const float scale2 = 0.08838834764831845f * 1.4426950408889634f;  // /sqrt(128) * log2e
  const float THR2   = 11.541560327111708f;                          // 8 * log2e

  const int vkv = (tid >> 3) * 2;       // 0..62
  const int vd0 = (tid & 7) * 16;       // 0..112
  const int vmask = (tid & 7) << 3;     // XOR swizzle ((d>>4)&7)<<3

  for (int pass = 0; pass < 2; ++pass) {
    const int qt = pass == 0 ? (31 - jq) : jq;
    const int q0 = qt * 64;
    const int nkt = qt + 1;

    short8 qf[4];
    {
      const ushort* qrow = Qb + (size_t)(q0 + w * 16 + l16) * DH;
#pragma unroll
      for (int ks = 0; ks < 4; ++ks) qf[ks] = *(const short8*)(qrow + ks * 32 + g * 8);
    }
    f32x4 oacc[8];
#pragma unroll
    for (int i = 0; i < 8; ++i) oacc[i] = (f32x4)0.f;
    float m_i[4], l_i[4];                 // l_i is a PER-LANE partial until epilogue
#pragma unroll
    for (int i = 0; i < 4; ++i) { m_i[i] = -INFINITY; l_i[i] = 0.f; }

#pragma unroll
    for (int it = 0; it < 4; ++it) {
      int ci = it * 256 + tid;
      int row = ci >> 4;
      int cb = ((ci & 15) * 16) ^ ((row & 7) << 4);
      async16(Kb + (size_t)row * DH + (cb >> 1), &Ks[0][ci * 8]);
    }
    {
      short8 vr[4];
      vr[0] = *(const short8*)(Vb + (size_t)vkv * DH + vd0);
      vr[1] = *(const short8*)(Vb + (size_t)vkv * DH + vd0 + 8);
      vr[2] = *(const short8*)(Vb + (size_t)(vkv + 1) * DH + vd0);
      vr[3] = *(const short8*)(Vb + (size_t)(vkv + 1) * DH + vd0 + 8);
#pragma unroll
      for (int j = 0; j < 16; ++j) {
        int d = vd0 + j;
        const ushort* a = (const ushort*)&vr[j >> 3];
        const ushort* c = (const ushort*)&vr[2 + (j >> 3)];
        unsigned val = (unsigned)a[j & 7] | ((unsigned)c[j & 7] << 16);
        *(unsigned*)&Vt[0][d * 72 + (vkv ^ vmask)] = val;
      }
    }
    __syncthreads();

    int cur = 0;
    for (int t = 0; t < nkt; ++t) {
      const int k0 = t * 64;
      const int nxt = cur ^ 1;
      const bool pre = (t + 1 < nkt);
      short8 vr[4];
      if (pre) {
        const int kn = (t + 1) * 64;
#pragma unroll
        for (int it = 0; it < 4; ++it) {
          int ci = it * 256 + tid;
          int row = ci >> 4;
          int cb = ((ci & 15) * 16) ^ ((row & 7) << 4);
          async16(Kb + (size_t)(kn + row) * DH + (cb >> 1), &Ks[nxt][ci * 8]);
        }
        vr[0] = *(const short8*)(Vb + (size_t)(kn + vkv) * DH + vd0);
        vr[1] = *(const short8*)(Vb + (size_t)(kn + vkv) * DH + vd0 + 8);
        vr[2] = *(const short8*)(Vb + (size_t)(kn + vkv + 1) * DH + vd0);
        vr[3] = *(const short8*)(Vb + (size_t)(kn + vkv + 1) * DH + vd0 + 8);
      }

      // ---- QK^T : S[16 q][64 keys] per wave ----
      f32x4 sacc[4];
#pragma unroll
      for (int nf = 0; nf < 4; ++nf) sacc[nf] = (f32x4)0.f;
      __builtin_amdgcn_s_setprio(1);
#pragma unroll
      for (int nf = 0; nf < 4; ++nf) {
        int row = nf * 16 + l16;
#pragma unroll
        for (int ks = 0; ks < 4; ++ks) {
          int cb = (ks * 64 + g * 16) ^ ((l16 & 7) << 4);
          short8 kf = *(const short8*)&Ks[cur][row * 128 + (cb >> 1)];
          sacc[nf] = __builtin_amdgcn_mfma_f32_16x16x32_bf16(qf[ks], kf, sacc[nf], 0, 0, 0);
        }
      }
      __builtin_amdgcn_s_setprio(0);

      // ---- online softmax, exp2 domain (diag-only mask; defer-max) ----
      float pv[4][4], mxr[4];
#pragma unroll
      for (int i = 0; i < 4; ++i)
#pragma unroll
        for (int nf = 0; nf < 4; ++nf) pv[i][nf] = sacc[nf][i] * scale2;
      if (t == nkt - 1) {                  // diagonal tile: apply causal mask
#pragma unroll
        for (int i = 0; i < 4; ++i) {
          int qrow = q0 + w * 16 + g * 4 + i;
#pragma unroll
          for (int nf = 0; nf < 4; ++nf)
            if (k0 + nf * 16 + l16 > qrow) pv[i][nf] = -INFINITY;
        }
      }
#pragma unroll
      for (int i = 0; i < 4; ++i) {
        float mx = fmaxf(fmaxf(pv[i][0], pv[i][1]), fmaxf(pv[i][2], pv[i][3]));
#pragma unroll
        for (int d = 1; d < 16; d <<= 1) mx = fmaxf(mx, __shfl_xor(mx, d, 64));
        mxr[i] = mx;
      }
      int need = 0;
#pragma unroll
      for (int i = 0; i < 4; ++i) need |= (mxr[i] > m_i[i] + THR2) ? 1 : 0;
      if (__any(need)) {
#pragma unroll
        for (int i = 0; i < 4; ++i) {
          float mnew = fmaxf(m_i[i], mxr[i]);
          float alpha = exp2f(m_i[i] - mnew);
          l_i[i] *= alpha;
          m_i[i] = mnew;
#pragma unroll
          for (int nf2 = 0; nf2 < 8; ++nf2) oacc[nf2][i] *= alpha;
        }
      }
#pragma unroll
      for (int i = 0; i < 4; ++i) {
        float p4[4];
#pragma unroll
        for (int nf = 0; nf < 4; ++nf) p4[nf] = exp2f(pv[i][nf] - m_i[i]);
        l_i[i] += (p4[0] + p4[1]) + (p4[2] + p4[3]);   // per-lane partial
#pragma unroll
        for (int nf = 0; nf < 4; ++nf)
          Ps[w][(g * 4 + i) * 72 + nf * 16 + l16] = f2bf(p4[nf]);
      }
      __asm__ volatile("s_waitcnt lgkmcnt(0)" ::: "memory");
      __builtin_amdgcn_sched_barrier(0);

      // ---- PV: O[16 q][128 dh] += P[16][64] @ V[64][128] ----
      __builtin_amdgcn_s_setprio(1);
#pragma unroll
      for (int kvh = 0; kvh < 2; ++kvh) {
        short8 pa = *(const short8*)&Ps[w][l16 * 72 + kvh * 32 + g * 8];
#pragma unroll
        for (int nf2 = 0; nf2 < 8; ++nf2) {
          int cb = (kvh * 32 + g * 8) ^ (nf2 * 8);
          short8 vf = *(const short8*)&Vt[cur][(nf2 * 16 + l16) * 72 + cb];
          oacc[nf2] = __builtin_amdgcn_mfma_f32_16x16x32_bf16(pa, vf, oacc[nf2], 0, 0, 0);
        }
      }
      __builtin_amdgcn_s_setprio(0);

      if (pre) {
#pragma unroll
        for (int j = 0; j < 16; ++j) {
          int d = vd0 + j;
          const ushort* a = (const ushort*)&vr[j >> 3];
          const ushort* c = (const ushort*)&vr[2 + (j >> 3)];
          unsigned val = (unsigned)a[j & 7] | ((unsigned)c[j & 7] << 16);
          *(unsigned*)&Vt[nxt][d * 72 + (vkv ^ vmask)] = val;
        }
      }
      __syncthreads();
      cur = nxt;
    }

    // ---- epilogue: single l-reduction across the 16-lane row group ----
#pragma unroll
    for (int i = 0; i < 4; ++i) {
      float sum = l_i[i];
#pragma unroll
      for (int d = 1; d < 16; d <<= 1) sum += __shfl_xor(sum, d, 64);
      float inv = 1.f / sum;
      int row = q0 + w * 16 + g * 4 + i;
      size_t obase = ((size_t)b * SEQ + row) * DMODEL + h * DH;
#pragma unroll
      for (int nf2 = 0; nf2 < 8; ++nf2)
        O[obase + nf2 * 16 + l16] = f2bf(oacc[nf2][i] * inv);
    }
  }
}

// ---------------- launch ----------------
extern "C" void kernel_launch(void* const* d_in, const int* in_sizes, int n_in,
                              void* d_out, int out_size, void* d_ws, size_t ws_size,
                              hipStream_t stream) {
  const float* x    = (const float*)d_in[0];
  const float* wqkv = (const float*)d_in[1];
  const float* wout = (const float*)d_in[2];
  const int*   spp  = (const int*)d_in[3];
  float* out = (float*)d_out;

  ushort* ws = (ushort*)d_ws;
  ushort* xb  = ws;                       // 8,388,608
  ushort* wqb = xb + 8388608;             // 12,582,912
  ushort* wob = wqb + 12582912;           // 4,194,304
  ushort* q   = wob + 4194304;            // 8,388,608
  ushort* k   = q + 8388608;
  ushort* v   = k + 8388608;
  ushort* ao  = v + 8388608;              // 8,388,608

  cast3_kernel<<<2048, 256, 0, stream>>>(x, wqkv, wout, xb, wqb, wob);

  // GEMM1: BM=256, BN=192, 4M x 2N waves; grid 32x16 = 512 = 2 exact rounds
  gemmk<0, 32, 256, 192, 4><<<dim3(6144 / 192, 4096 / 256, 1), 512, 0, stream>>>(
      xb, wqb, 6144, q, k, v, nullptr);

  rope_kernel<<<4194304 / 256, 256, 0, stream>>>(q, k, spp);

  // attn: flat 512 blocks, XCD-pinned (b,h) for L2-resident KV
  attn_kernel<<<dim3(512, 1, 1), 256, 0, stream>>>(q, k, v, ao);

  // GEMM2: BM=128, BN=256, 2M x 4N; grid 8x32 = 256 = 1 exact round, full K
  gemmk<1, 32, 128, 256, 2><<<dim3(2048 / 256, 4096 / 128, 1), 512, 0, stream>>>(
      ao, wob, 2048, nullptr, nullptr, nullptr, out);
}

// Round 23
// 242.304 us; speedup vs baseline: 1.1399x; 1.0428x over previous
//
#include <hip/hip_runtime.h>

typedef unsigned short ushort;
typedef __attribute__((ext_vector_type(8))) short short8;
typedef __attribute__((ext_vector_type(4))) float f32x4;

#define NH 16
#define DH 128
#define SEQ 2048
#define DMODEL 2048
#define GK 2048   // K dim for both GEMMs

__device__ __forceinline__ ushort f2bf(float f) {
  union { float f; unsigned u; } v; v.f = f;
  unsigned u = v.u;
  unsigned r = (u + 0x7fffu + ((u >> 16) & 1u)) >> 16;
  return (ushort)r;
}
__device__ __forceinline__ float bf2f(ushort h) {
  union { unsigned u; float f; } v; v.u = ((unsigned)h) << 16; return v.f;
}

__device__ __forceinline__ void async16(const ushort* g, ushort* l) {
  __builtin_amdgcn_global_load_lds(
      (const __attribute__((address_space(1))) unsigned*)g,
      (__attribute__((address_space(3))) unsigned*)l, 16, 0, 0);
}

// ---------------- fused cast fp32 -> bf16 for x, wqkv, wout ----------------
#define NX  2097152   // x      f4 count
#define NWQ 3145728   // wqkv   f4 count
#define NWO 1048576   // wout   f4 count
__global__ void cast3_kernel(const float* __restrict__ x, const float* __restrict__ wq,
                             const float* __restrict__ wo, ushort* __restrict__ xb,
                             ushort* __restrict__ wqb, ushort* __restrict__ wob) {
  int i = blockIdx.x * blockDim.x + threadIdx.x;
  int stride = gridDim.x * blockDim.x;
  for (; i < NX + NWQ + NWO; i += stride) {
    const float* s; ushort* d; int j;
    if (i < NX)            { s = x;  d = xb;  j = i; }
    else if (i < NX + NWQ) { s = wq; d = wqb; j = i - NX; }
    else                   { s = wo; d = wob; j = i - NX - NWQ; }
    float4 v = ((const float4*)s)[j];
    unsigned long long p = (unsigned long long)f2bf(v.x)
                         | ((unsigned long long)f2bf(v.y) << 16)
                         | ((unsigned long long)f2bf(v.z) << 32)
                         | ((unsigned long long)f2bf(v.w) << 48);
    ((unsigned long long*)d)[j] = p;
  }
}

// ---------------- BMxBN GEMM, reg-staged 2-tile-deep pipeline ----------------
// 512 threads = 8 waves arranged WM(M) x (8/WM)(N); wave tile (BM/WM) x (BN*WM/8).
// BK=64, 2 LDS slots, global->VGPR->LDS staging, 1 barrier/K-tile.
template<int MODE, int NTK, int BM, int BN, int WM>
__global__ __launch_bounds__(512, 1)
void gemmk(const ushort* __restrict__ A, const ushort* __restrict__ B, int N,
           ushort* __restrict__ oq, ushort* __restrict__ ok, ushort* __restrict__ ov,
           float* __restrict__ of) {
  constexpr int WNW = 8 / WM;              // waves in N
  constexpr int MF = BM / (WM * 16);       // M frags / wave
  constexpr int NF = BN / (WNW * 16);      // N frags / wave
  constexpr int AC = BM / 64;              // A staging chunks / thread
  constexpr int BC = BN / 64;              // B staging chunks / thread
  __shared__ ushort As[2][BM * 64];
  __shared__ ushort Bs[2][BN * 64];
  const int tid = threadIdx.x;
  const int lane = tid & 63;
  const int w = tid >> 6;
  const int wm = w / WNW, wn = w % WNW;
  const int g = lane >> 4, l16 = lane & 15;
  const int m0 = blockIdx.y * BM;
  const int n0 = blockIdx.x * BN;
  const ushort* Ablk = A + (size_t)m0 * GK;
  const ushort* Bblk = B + (size_t)n0 * GK;

  const int r0 = tid >> 3, sl = tid & 7;
  const int gcol = ((sl * 16) ^ ((r0 & 7) << 4)) >> 1;
  const int ldsb = r0 * 64 + sl * 8;

  f32x4 acc[MF][NF];
#pragma unroll
  for (int mf = 0; mf < MF; ++mf)
#pragma unroll
    for (int nf = 0; nf < NF; ++nf) acc[mf][nf] = (f32x4)0.f;

  short8 ra[AC], rb[BC];
#pragma unroll
  for (int j = 0; j < AC; ++j)
    ra[j] = *(const short8*)(Ablk + (size_t)(j * 64 + r0) * GK + gcol);
#pragma unroll
  for (int j = 0; j < BC; ++j)
    rb[j] = *(const short8*)(Bblk + (size_t)(j * 64 + r0) * GK + gcol);
#pragma unroll
  for (int j = 0; j < AC; ++j) *(short8*)&As[0][j * 4096 + ldsb] = ra[j];
#pragma unroll
  for (int j = 0; j < BC; ++j) *(short8*)&Bs[0][j * 4096 + ldsb] = rb[j];
#pragma unroll
  for (int j = 0; j < AC; ++j)
    ra[j] = *(const short8*)(Ablk + (size_t)(j * 64 + r0) * GK + 64 + gcol);
#pragma unroll
  for (int j = 0; j < BC; ++j)
    rb[j] = *(const short8*)(Bblk + (size_t)(j * 64 + r0) * GK + 64 + gcol);
#pragma unroll
  for (int j = 0; j < AC; ++j) *(short8*)&As[1][j * 4096 + ldsb] = ra[j];
#pragma unroll
  for (int j = 0; j < BC; ++j) *(short8*)&Bs[1][j * 4096 + ldsb] = rb[j];
  __syncthreads();

  for (int t = 0; t < NTK; ++t) {
    const bool pre = (t + 2 < NTK);
    if (pre) {
      const int kt = (t + 2) * 64;
#pragma unroll
      for (int j = 0; j < AC; ++j)
        ra[j] = *(const short8*)(Ablk + (size_t)(j * 64 + r0) * GK + kt + gcol);
#pragma unroll
      for (int j = 0; j < BC; ++j)
        rb[j] = *(const short8*)(Bblk + (size_t)(j * 64 + r0) * GK + kt + gcol);
    }
    __builtin_amdgcn_sched_barrier(0);     // pin load issue before compute

    const ushort* cA = As[t & 1];
    const ushort* cB = Bs[t & 1];
    short8 bfr[NF][2];
#pragma unroll
    for (int nf = 0; nf < NF; ++nf) {
      int row = wn * (BN / WNW) + nf * 16 + l16;
#pragma unroll
      for (int ks = 0; ks < 2; ++ks)
        bfr[nf][ks] = *(const short8*)&cB[row * 64 + (((ks * 64 + g * 16) ^ ((l16 & 7) << 4)) >> 1)];
    }
#pragma unroll
    for (int p = 0; p < MF / 2; ++p) {
      short8 af[2][2];
#pragma unroll
      for (int mi = 0; mi < 2; ++mi) {
        int row = wm * (BM / WM) + (2 * p + mi) * 16 + l16;
#pragma unroll
        for (int ks = 0; ks < 2; ++ks)
          af[mi][ks] = *(const short8*)&cA[row * 64 + (((ks * 64 + g * 16) ^ ((l16 & 7) << 4)) >> 1)];
      }
      __builtin_amdgcn_s_setprio(1);
#pragma unroll
      for (int mi = 0; mi < 2; ++mi)
#pragma unroll
        for (int nf = 0; nf < NF; ++nf)
#pragma unroll
          for (int ks = 0; ks < 2; ++ks)
            acc[2 * p + mi][nf] = __builtin_amdgcn_mfma_f32_16x16x32_bf16(
                af[mi][ks], bfr[nf][ks], acc[2 * p + mi][nf], 0, 0, 0);
      __builtin_amdgcn_s_setprio(0);
    }

    __syncthreads();                       // readers done + vmcnt drain
    if (pre) {
      ushort* nA = (ushort*)As[t & 1];
      ushort* nB = (ushort*)Bs[t & 1];
#pragma unroll
      for (int j = 0; j < AC; ++j) *(short8*)&nA[j * 4096 + ldsb] = ra[j];
#pragma unroll
      for (int j = 0; j < BC; ++j) *(short8*)&nB[j * 4096 + ldsb] = rb[j];
    }
  }

#pragma unroll
  for (int mf = 0; mf < MF; ++mf)
#pragma unroll
    for (int nf = 0; nf < NF; ++nf)
#pragma unroll
      for (int i = 0; i < 4; ++i) {
        int row = m0 + wm * (BM / WM) + mf * 16 + g * 4 + i;
        int col = n0 + wn * (BN / WNW) + nf * 16 + l16;
        float val = acc[mf][nf][i];
        if (MODE == 0) {
          int which = col >> 11;
          int r = col & 2047;
          int h = r >> 7, dh = r & 127;
          int b = row >> 11, s = row & 2047;
          size_t dst = ((size_t)(b * NH + h) * SEQ + s) * DH + dh;
          ushort* o = (which == 0) ? oq : (which == 1 ? ok : ov);
          o[dst] = f2bf(val);
        } else {
          of[(size_t)row * N + col] = val;
        }
      }
}

// ---------------- RoPE (in-place on head-major bf16 q,k) ----------------
__global__ void rope_kernel(ushort* __restrict__ q, ushort* __restrict__ k,
                            const int* __restrict__ spp) {
  int id = blockIdx.x * blockDim.x + threadIdx.x;   // < B*H*S*64
  int j = id & 63;
  int s = (id >> 6) & (SEQ - 1);
  int bh = id >> 17;
  size_t base = ((size_t)bh * SEQ + s) * DH;
  float pos = (float)(s + spp[0]);
  float ang = pos * __expf(-(float)j * (9.210340371976184f / 64.f)); // 1/10000^(j/64)
  float c = cosf(ang), sn = sinf(ang);
  float q1 = bf2f(q[base + j]), q2 = bf2f(q[base + 64 + j]);
  q[base + j]      = f2bf(q1 * c - q2 * sn);
  q[base + 64 + j] = f2bf(q2 * c + q1 * sn);
  float k1 = bf2f(k[base + j]), k2 = bf2f(k[base + 64 + j]);
  k[base + j]      = f2bf(k1 * c - k2 * sn);
  k[base + 64 + j] = f2bf(k2 * c + k1 * sn);
}

// ---------------- causal flash attention (r22 core + lazy row-max) ----------
// XCD-pinned flat grid 512 (all 16 q-blocks of one (b,h) on one XCD).
// Defer-max with a LAZY threshold test: rowmax > m+THR  <=>  some lane's
// 4-value max > m+THR, so the common path uses 3 fmax + __any (no LDS-hop
// shuffle chain).  The full 16-lane shuffle reduce runs only when the branch
// fires (tile 0 and rare max-growth) -- m_i stays wave-uniform, so per-lane
// l partials remain valid.
__global__ __launch_bounds__(256, 2)
void attn_kernel(const ushort* __restrict__ Q, const ushort* __restrict__ K,
                 const ushort* __restrict__ V, ushort* __restrict__ O) {
  __shared__ ushort Ks[2][64 * 128];     // 32 KB
  __shared__ ushort Vt[2][128 * 72];     // 36 KB
  __shared__ ushort Ps[4][16 * 72];      // 9 KB
  const int tid = threadIdx.x;
  const int lane = tid & 63;
  const int w = tid >> 6;
  const int g = lane >> 4, l16 = lane & 15;
  const int fid = (int)blockIdx.x;       // 0..511
  const int xcd = fid & 7;
  const int s8 = fid >> 3;               // 0..63
  const int pl = s8 >> 4;                // 0..3
  const int jq = s8 & 15;                // 0..15
  const int p = xcd * 4 + pl;            // 0..31 : (b,h) pair
  const int b = p >> 4, h = p & 15;
  const int bh = b * NH + h;
  const ushort* Qb = Q + (size_t)bh * SEQ * DH;
  const ushort* Kb = K + (size_t)bh * SEQ * DH;
  const ushort* Vb = V + (size_t)bh * SEQ * DH;
  const float scale2 = 0.08838834764831845f * 1.4426950408889634f;  // /sqrt(128) * log2e
  const float THR2   = 11.541560327111708f;                          // 8 * log2e

  const int vkv = (tid >> 3) * 2;       // 0..62
  const int vd0 = (tid & 7) * 16;       // 0..112
  const int vmask = (tid & 7) << 3;     // XOR swizzle ((d>>4)&7)<<3

  for (int pass = 0; pass < 2; ++pass) {
    const int qt = pass == 0 ? (31 - jq) : jq;
    const int q0 = qt * 64;
    const int nkt = qt + 1;

    short8 qf[4];
    {
      const ushort* qrow = Qb + (size_t)(q0 + w * 16 + l16) * DH;
#pragma unroll
      for (int ks = 0; ks < 4; ++ks) qf[ks] = *(const short8*)(qrow + ks * 32 + g * 8);
    }
    f32x4 oacc[8];
#pragma unroll
    for (int i = 0; i < 8; ++i) oacc[i] = (f32x4)0.f;
    float m_i[4], l_i[4];                 // l_i is a PER-LANE partial until epilogue
#pragma unroll
    for (int i = 0; i < 4; ++i) { m_i[i] = -INFINITY; l_i[i] = 0.f; }

#pragma unroll
    for (int it = 0; it < 4; ++it) {
      int ci = it * 256 + tid;
      int row = ci >> 4;
      int cb = ((ci & 15) * 16) ^ ((row & 7) << 4);
      async16(Kb + (size_t)row * DH + (cb >> 1), &Ks[0][ci * 8]);
    }
    {
      short8 vr[4];
      vr[0] = *(const short8*)(Vb + (size_t)vkv * DH + vd0);
      vr[1] = *(const short8*)(Vb + (size_t)vkv * DH + vd0 + 8);
      vr[2] = *(const short8*)(Vb + (size_t)(vkv + 1) * DH + vd0);
      vr[3] = *(const short8*)(Vb + (size_t)(vkv + 1) * DH + vd0 + 8);
#pragma unroll
      for (int j = 0; j < 16; ++j) {
        int d = vd0 + j;
        const ushort* a = (const ushort*)&vr[j >> 3];
        const ushort* c = (const ushort*)&vr[2 + (j >> 3)];
        unsigned val = (unsigned)a[j & 7] | ((unsigned)c[j & 7] << 16);
        *(unsigned*)&Vt[0][d * 72 + (vkv ^ vmask)] = val;
      }
    }
    __syncthreads();

    int cur = 0;
    for (int t = 0; t < nkt; ++t) {
      const int k0 = t * 64;
      const int nxt = cur ^ 1;
      const bool pre = (t + 1 < nkt);
      short8 vr[4];
      if (pre) {
        const int kn = (t + 1) * 64;
#pragma unroll
        for (int it = 0; it < 4; ++it) {
          int ci = it * 256 + tid;
          int row = ci >> 4;
          int cb = ((ci & 15) * 16) ^ ((row & 7) << 4);
          async16(Kb + (size_t)(kn + row) * DH + (cb >> 1), &Ks[nxt][ci * 8]);
        }
        vr[0] = *(const short8*)(Vb + (size_t)(kn + vkv) * DH + vd0);
        vr[1] = *(const short8*)(Vb + (size_t)(kn + vkv) * DH + vd0 + 8);
        vr[2] = *(const short8*)(Vb + (size_t)(kn + vkv + 1) * DH + vd0);
        vr[3] = *(const short8*)(Vb + (size_t)(kn + vkv + 1) * DH + vd0 + 8);
      }

      // ---- QK^T : S[16 q][64 keys] per wave ----
      f32x4 sacc[4];
#pragma unroll
      for (int nf = 0; nf < 4; ++nf) sacc[nf] = (f32x4)0.f;
      __builtin_amdgcn_s_setprio(1);
#pragma unroll
      for (int nf = 0; nf < 4; ++nf) {
        int row = nf * 16 + l16;
#pragma unroll
        for (int ks = 0; ks < 4; ++ks) {
          int cb = (ks * 64 + g * 16) ^ ((l16 & 7) << 4);
          short8 kf = *(const short8*)&Ks[cur][row * 128 + (cb >> 1)];
          sacc[nf] = __builtin_amdgcn_mfma_f32_16x16x32_bf16(qf[ks], kf, sacc[nf], 0, 0, 0);
        }
      }
      __builtin_amdgcn_s_setprio(0);

      // ---- online softmax, exp2 domain, LAZY row-max (diag-only mask) ----
      float pv[4][4], lmax[4];
#pragma unroll
      for (int i = 0; i < 4; ++i)
#pragma unroll
        for (int nf = 0; nf < 4; ++nf) pv[i][nf] = sacc[nf][i] * scale2;
      if (t == nkt - 1) {                  // diagonal tile: apply causal mask
#pragma unroll
        for (int i = 0; i < 4; ++i) {
          int qrow = q0 + w * 16 + g * 4 + i;
#pragma unroll
          for (int nf = 0; nf < 4; ++nf)
            if (k0 + nf * 16 + l16 > qrow) pv[i][nf] = -INFINITY;
        }
      }
      // per-lane 4-value max only (no cross-lane reduce in the common path)
#pragma unroll
      for (int i = 0; i < 4; ++i)
        lmax[i] = fmaxf(fmaxf(pv[i][0], pv[i][1]), fmaxf(pv[i][2], pv[i][3]));
      int need = 0;
#pragma unroll
      for (int i = 0; i < 4; ++i) need |= (lmax[i] > m_i[i] + THR2) ? 1 : 0;
      if (__any(need)) {                   // rare: full reduce + rescale
#pragma unroll
        for (int i = 0; i < 4; ++i) {
          float mx = lmax[i];
#pragma unroll
          for (int d = 1; d < 16; d <<= 1) mx = fmaxf(mx, __shfl_xor(mx, d, 64));
          float mnew = fmaxf(m_i[i], mx);
          float alpha = exp2f(m_i[i] - mnew);
          l_i[i] *= alpha;
          m_i[i] = mnew;
#pragma unroll
          for (int nf2 = 0; nf2 < 8; ++nf2) oacc[nf2][i] *= alpha;
        }
      }
#pragma unroll
      for (int i = 0; i < 4; ++i) {
        float p4[4];
#pragma unroll
        for (int nf = 0; nf < 4; ++nf) p4[nf] = exp2f(pv[i][nf] - m_i[i]);
        l_i[i] += (p4[0] + p4[1]) + (p4[2] + p4[3]);   // per-lane partial
#pragma unroll
        for (int nf = 0; nf < 4; ++nf)
          Ps[w][(g * 4 + i) * 72 + nf * 16 + l16] = f2bf(p4[nf]);
      }
      __asm__ volatile("s_waitcnt lgkmcnt(0)" ::: "memory");
      __builtin_amdgcn_sched_barrier(0);

      // ---- PV: O[16 q][128 dh] += P[16][64] @ V[64][128] ----
      __builtin_amdgcn_s_setprio(1);
#pragma unroll
      for (int kvh = 0; kvh < 2; ++kvh) {
        short8 pa = *(const short8*)&Ps[w][l16 * 72 + kvh * 32 + g * 8];
#pragma unroll
        for (int nf2 = 0; nf2 < 8; ++nf2) {
          int cb = (kvh * 32 + g * 8) ^ (nf2 * 8);
          short8 vf = *(const short8*)&Vt[cur][(nf2 * 16 + l16) * 72 + cb];
          oacc[nf2] = __builtin_amdgcn_mfma_f32_16x16x32_bf16(pa, vf, oacc[nf2], 0, 0, 0);
        }
      }
      __builtin_amdgcn_s_setprio(0);

      if (pre) {
#pragma unroll
        for (int j = 0; j < 16; ++j) {
          int d = vd0 + j;
          const ushort* a = (const ushort*)&vr[j >> 3];
          const ushort* c = (const ushort*)&vr[2 + (j >> 3)];
          unsigned val = (unsigned)a[j & 7] | ((unsigned)c[j & 7] << 16);
          *(unsigned*)&Vt[nxt][d * 72 + (vkv ^ vmask)] = val;
        }
      }
      __syncthreads();
      cur = nxt;
    }

    // ---- epilogue: single l-reduction across the 16-lane row group ----
#pragma unroll
    for (int i = 0; i < 4; ++i) {
      float sum = l_i[i];
#pragma unroll
      for (int d = 1; d < 16; d <<= 1) sum += __shfl_xor(sum, d, 64);
      float inv = 1.f / sum;
      int row = q0 + w * 16 + g * 4 + i;
      size_t obase = ((size_t)b * SEQ + row) * DMODEL + h * DH;
#pragma unroll
      for (int nf2 = 0; nf2 < 8; ++nf2)
        O[obase + nf2 * 16 + l16] = f2bf(oacc[nf2][i] * inv);
    }
  }
}

// ---------------- launch ----------------
extern "C" void kernel_launch(void* const* d_in, const int* in_sizes, int n_in,
                              void* d_out, int out_size, void* d_ws, size_t ws_size,
                              hipStream_t stream) {
  const float* x    = (const float*)d_in[0];
  const float* wqkv = (const float*)d_in[1];
  const float* wout = (const float*)d_in[2];
  const int*   spp  = (const int*)d_in[3];
  float* out = (float*)d_out;

  ushort* ws = (ushort*)d_ws;
  ushort* xb  = ws;                       // 8,388,608
  ushort* wqb = xb + 8388608;             // 12,582,912
  ushort* wob = wqb + 12582912;           // 4,194,304
  ushort* q   = wob + 4194304;            // 8,388,608
  ushort* k   = q + 8388608;
  ushort* v   = k + 8388608;
  ushort* ao  = v + 8388608;              // 8,388,608

  cast3_kernel<<<2048, 256, 0, stream>>>(x, wqkv, wout, xb, wqb, wob);

  // GEMM1: BM=256, BN=192, 4M x 2N waves; grid 32x16 = 512 = 2 exact rounds
  gemmk<0, 32, 256, 192, 4><<<dim3(6144 / 192, 4096 / 256, 1), 512, 0, stream>>>(
      xb, wqb, 6144, q, k, v, nullptr);

  rope_kernel<<<4194304 / 256, 256, 0, stream>>>(q, k, spp);

  // attn: flat 512 blocks, XCD-pinned (b,h) for L2-resident KV
  attn_kernel<<<dim3(512, 1, 1), 256, 0, stream>>>(q, k, v, ao);

  // GEMM2: BM=128, BN=256, 2M x 4N; grid 8x32 = 256 = 1 exact round, full K
  gemmk<1, 32, 128, 256, 2><<<dim3(2048 / 256, 4096 / 128, 1), 512, 0, stream>>>(
      ao, wob, 2048, nullptr, nullptr, nullptr, out);
}